// Round 1
// baseline (1004.859 us; speedup 1.0000x reference)
//
#include <hip/hip_runtime.h>
#include <math.h>

typedef _Float16 f16;
typedef _Float16 f16x8 __attribute__((ext_vector_type(8)));
typedef _Float16 f16x4 __attribute__((ext_vector_type(4)));
typedef float f32x4 __attribute__((ext_vector_type(4)));

#define D2 1024
#define NB 16
#define NP 2048
#define M_ROWS 32768  // P*B

// ---------------- ws layout (bytes) ----------------
#define OFF_ABSMAX 0u
#define OFF_TQ     256u
#define OFF_TO     512u
#define OFF_QBIAS  1024u        // 4*1024 f32
#define OFF_XQH    32768u       // 16*1024 f16
#define OFF_XQL    65536u
#define OFF_XOH    98304u
#define OFF_XOL    131072u
#define OFF_QBUF   163840u      // 16*1024 f32
#define OFF_ATT    229376u      // 16*1024 f32
#define OFF_WH     1048576u     // 4 * 1M f16 = 8 MB
#define OFF_TK     9437184u     // 32768*4 f32
#define OFF_TV     9961472u
#define OFF_KV     10485760u

__device__ __forceinline__ float qint_of(float w, float scale) {
    return fminf(7.f, fmaxf(-8.f, rintf(w / (scale + 1e-8f))));
}

// ---------------- absmax over 4 weight matrices ----------------
__global__ void __launch_bounds__(256) absmax_kernel(
    const float* __restrict__ W0, const float* __restrict__ W1,
    const float* __restrict__ W2, const float* __restrict__ W3,
    unsigned* __restrict__ absmax) {
  int mat = blockIdx.x >> 6;
  int blk = blockIdx.x & 63;
  const float* W = mat == 0 ? W0 : mat == 1 ? W1 : mat == 2 ? W2 : W3;
  int tid = blk * 256 + threadIdx.x;      // 0..16383
  const float4* W4 = (const float4*)W;
  float m = 0.f;
  #pragma unroll
  for (int i = 0; i < 16; ++i) {
    float4 v = W4[tid + i * 16384];
    m = fmaxf(m, fmaxf(fmaxf(fabsf(v.x), fabsf(v.y)), fmaxf(fabsf(v.z), fabsf(v.w))));
  }
  #pragma unroll
  for (int k = 32; k >= 1; k >>= 1) m = fmaxf(m, __shfl_xor(m, k));
  __shared__ float sm[4];
  if ((threadIdx.x & 63) == 0) sm[threadIdx.x >> 6] = m;
  __syncthreads();
  if (threadIdx.x == 0) {
    m = fmaxf(fmaxf(sm[0], sm[1]), fmaxf(sm[2], sm[3]));
    atomicMax(&absmax[mat], __float_as_uint(m));
  }
}

// ---------------- quantize biases (simq) ----------------
__global__ void __launch_bounds__(256) bias_quant_kernel(
    const float* __restrict__ b0, const float* __restrict__ b1,
    const float* __restrict__ b2, const float* __restrict__ b3,
    float* __restrict__ qbias) {
  int mat = blockIdx.x;
  const float* bb = mat == 0 ? b0 : mat == 1 ? b1 : mat == 2 ? b2 : b3;
  int t = threadIdx.x;
  float4 v = ((const float4*)bb)[t];
  float m = fmaxf(fmaxf(fabsf(v.x), fabsf(v.y)), fmaxf(fabsf(v.z), fabsf(v.w)));
  #pragma unroll
  for (int k = 32; k >= 1; k >>= 1) m = fmaxf(m, __shfl_xor(m, k));
  __shared__ float sm[4];
  if ((t & 63) == 0) sm[t >> 6] = m;
  __syncthreads();
  float M = fmaxf(fmaxf(sm[0], sm[1]), fmaxf(sm[2], sm[3]));
  float scale = M * (1.0f / 7.0f);
  float4 q;
  q.x = (M == 0.f) ? v.x : qint_of(v.x, scale) * scale;
  q.y = (M == 0.f) ? v.y : qint_of(v.y, scale) * scale;
  q.z = (M == 0.f) ? v.z : qint_of(v.z, scale) * scale;
  q.w = (M == 0.f) ? v.w : qint_of(v.w, scale) * scale;
  ((float4*)(qbias + mat * 1024))[t] = q;
}

// ---------------- quantize W -> f16 integer values ----------------
__global__ void __launch_bounds__(256) quantW_kernel(
    const float* __restrict__ W0, const float* __restrict__ W1,
    const float* __restrict__ W2, const float* __restrict__ W3,
    const unsigned* __restrict__ absmax, f16* __restrict__ Wh) {
  int gid = blockIdx.x * 256 + threadIdx.x;  // 0..1048575 (float4 units)
  int mat = gid >> 18;
  int idx = gid & 262143;
  const float* W = mat == 0 ? W0 : mat == 1 ? W1 : mat == 2 ? W2 : W3;
  float scale = __uint_as_float(absmax[mat]) * (1.0f / 7.0f);
  float4 v = ((const float4*)W)[idx];
  f16x4 r;
  r[0] = (f16)qint_of(v.x, scale);
  r[1] = (f16)qint_of(v.y, scale);
  r[2] = (f16)qint_of(v.z, scale);
  r[3] = (f16)qint_of(v.w, scale);
  *(f16x4*)(Wh + (size_t)mat * 1048576 + (size_t)idx * 4) = r;
}

// ---------------- f32 -> f16 hi/lo split (16K elems) ----------------
__global__ void __launch_bounds__(256) cvt_hilo_kernel(
    const float* __restrict__ x, f16* __restrict__ hi, f16* __restrict__ lo) {
  int i = blockIdx.x * 256 + threadIdx.x;  // float4 idx, 4096 total
  float4 v = ((const float4*)x)[i];
  f16 h0 = (f16)v.x, h1 = (f16)v.y, h2 = (f16)v.z, h3 = (f16)v.w;
  f16x4 hv = {h0, h1, h2, h3};
  f16x4 lv = {(f16)(v.x - (float)h0), (f16)(v.y - (float)h1),
              (f16)(v.z - (float)h2), (f16)(v.w - (float)h3)};
  *(f16x4*)(hi + (size_t)i * 4) = hv;
  *(f16x4*)(lo + (size_t)i * 4) = lv;
}

// ---------------- lora t for 16-row x: t[16][4] ----------------
__global__ void __launch_bounds__(256) lora_t_small_kernel(
    const float* __restrict__ x, const float* __restrict__ A, float* __restrict__ t) {
  int tt = threadIdx.x;
  int b = tt >> 4;            // 0..15
  int r = (tt >> 2) & 3;      // 0..3
  int s = tt & 3;             // k quarter
  const float4* xv = (const float4*)(x + b * 1024 + s * 256);
  const float4* av = (const float4*)(A + r * 1024 + s * 256);
  float acc = 0.f;
  #pragma unroll 4
  for (int i = 0; i < 64; ++i) {
    float4 a = xv[i], c = av[i];
    acc += a.x * c.x + a.y * c.y + a.z * c.z + a.w * c.w;
  }
  acc += __shfl_xor(acc, 1);
  acc += __shfl_xor(acc, 2);
  if (s == 0) t[b * 4 + r] = acc;
}

// ---------------- lora t for z_past: t_k/t_v [32768][4] ----------------
__global__ void __launch_bounds__(256) lora_t_big_kernel(
    const float* __restrict__ zp, const float* __restrict__ Ak,
    const float* __restrict__ Av, float* __restrict__ tk, float* __restrict__ tv) {
  __shared__ float sA[8 * 1024];
  for (int i = 0; i < 8; ++i) {
    int f4 = threadIdx.x + i * 256;  // 0..2047
    float4 v = (f4 < 1024) ? ((const float4*)Ak)[f4] : ((const float4*)Av)[f4 - 1024];
    ((float4*)sA)[f4] = v;
  }
  __syncthreads();
  int lane = threadIdx.x & 63, wave = threadIdx.x >> 6;
  for (int it = 0; it < 4; ++it) {
    int m = blockIdx.x * 16 + wave * 4 + it;
    const float4* xr = (const float4*)(zp + (size_t)m * 1024);
    float acc[8] = {0.f, 0.f, 0.f, 0.f, 0.f, 0.f, 0.f, 0.f};
    for (int c = lane; c < 256; c += 64) {
      float4 xv = xr[c];
      #pragma unroll
      for (int r = 0; r < 8; ++r) {
        float4 a = ((const float4*)sA)[r * 256 + c];
        acc[r] += xv.x * a.x + xv.y * a.y + xv.z * a.z + xv.w * a.w;
      }
    }
    #pragma unroll
    for (int k = 32; k >= 1; k >>= 1) {
      #pragma unroll
      for (int r = 0; r < 8; ++r) acc[r] += __shfl_xor(acc[r], k);
    }
    if (lane == 0) {
      tk[m * 4 + 0] = acc[0]; tk[m * 4 + 1] = acc[1];
      tk[m * 4 + 2] = acc[2]; tk[m * 4 + 3] = acc[3];
      tv[m * 4 + 0] = acc[4]; tv[m * 4 + 1] = acc[5];
      tv[m * 4 + 2] = acc[6]; tv[m * 4 + 3] = acc[7];
    }
  }
}

// ---------------- MFMA GEMV (M=16): out = scale*(x@Wq^T) + bias + lora ----------------
__global__ void __launch_bounds__(256) gemv_mfma_kernel(
    const f16* __restrict__ xhi, const f16* __restrict__ xlo,
    const f16* __restrict__ Wm, const unsigned* __restrict__ absmax, int mat,
    const float* __restrict__ qb, const float* __restrict__ t,
    const float* __restrict__ LB, float* __restrict__ out) {
  int wave = threadIdx.x >> 6, lane = threadIdx.x & 63;
  int nf = blockIdx.x * 4 + wave;
  int n0 = nf * 16;
  int row = lane & 15, kq = lane >> 4;
  f32x4 acc = {0.f, 0.f, 0.f, 0.f};
  const f16* xh = xhi + row * 1024 + kq * 8;
  const f16* xl = xlo + row * 1024 + kq * 8;
  const f16* wp = Wm + (size_t)(n0 + row) * 1024 + kq * 8;
  #pragma unroll 4
  for (int k0 = 0; k0 < 1024; k0 += 32) {
    f16x8 ah = *(const f16x8*)(xh + k0);
    f16x8 al = *(const f16x8*)(xl + k0);
    f16x8 bb = *(const f16x8*)(wp + k0);
    acc = __builtin_amdgcn_mfma_f32_16x16x32_f16(ah, bb, acc, 0, 0, 0);
    acc = __builtin_amdgcn_mfma_f32_16x16x32_f16(al, bb, acc, 0, 0, 0);
  }
  float scale = __uint_as_float(absmax[mat]) * (1.0f / 7.0f);
  int col = n0 + row;
  float bias = qb[col];
  float4 lb = *(const float4*)(LB + col * 4);
  #pragma unroll
  for (int j = 0; j < 4; ++j) {
    int m = kq * 4 + j;
    float4 tv = *(const float4*)(t + m * 4);
    out[m * 1024 + col] =
        scale * acc[j] + bias + 4.0f * (tv.x * lb.x + tv.y * lb.y + tv.z * lb.z + tv.w * lb.w);
  }
}

// ---------------- fused K+V projection GEMM ----------------
template <typename KVT>
__global__ void __launch_bounds__(256, 2) kv_gemm_kernel(
    const float* __restrict__ zp, const f16* __restrict__ Wh,
    const unsigned* __restrict__ absmax, const float* __restrict__ qbias,
    const float* __restrict__ tk, const float* __restrict__ tv,
    const float* __restrict__ LBk, const float* __restrict__ LBv,
    KVT* __restrict__ kout, KVT* __restrict__ vout) {
  __shared__ __align__(16) f16 sAh[128][40];  // pad stride 40 halfs -> 2-way max on frag reads
  __shared__ __align__(16) f16 sAl[128][40];
  __shared__ __align__(16) f16 sB[128][40];
  __shared__ float sT[128][4];

  int m0 = blockIdx.x * 128;
  int nb = blockIdx.y;
  bool is_v = nb >= 8;
  int n0 = (nb & 7) * 128;
  int mat = is_v ? 2 : 1;
  const f16* Wm = Wh + (size_t)mat * 1048576;
  const float* ttv = is_v ? tv : tk;
  const float* LBm = is_v ? LBv : LBk;
  const float* qb = qbias + mat * 1024;
  KVT* outp = is_v ? vout : kout;

  int tid = threadIdx.x;
  int lane = tid & 63, wave = tid >> 6;
  int wm = (wave >> 1) * 64, wn = (wave & 1) * 64;
  int row = lane & 15, kq = lane >> 4;

  f32x4 acc[4][4];
  #pragma unroll
  for (int i = 0; i < 4; ++i)
    #pragma unroll
    for (int j = 0; j < 4; ++j) acc[i][j] = (f32x4){0.f, 0.f, 0.f, 0.f};

  int sr = tid >> 1, seg = tid & 1;
  const float* asrc = zp + (size_t)(m0 + sr) * 1024 + seg * 16;
  const f16* bsrc = Wm + (size_t)(n0 + sr) * 1024 + seg * 16;

  for (int k0 = 0; k0 < 1024; k0 += 32) {
    __syncthreads();
    // --- stage A (f32 -> f16 hi/lo) ---
    float xs[16];
    const float4* a4 = (const float4*)(asrc + k0);
    *(float4*)&xs[0] = a4[0];
    *(float4*)&xs[4] = a4[1];
    *(float4*)&xs[8] = a4[2];
    *(float4*)&xs[12] = a4[3];
    f16 hs[16], ls[16];
    #pragma unroll
    for (int i = 0; i < 16; ++i) {
      f16 h = (f16)xs[i];
      hs[i] = h;
      ls[i] = (f16)(xs[i] - (float)h);
    }
    *(f16x8*)&sAh[sr][seg * 16] = *(f16x8*)&hs[0];
    *(f16x8*)&sAh[sr][seg * 16 + 8] = *(f16x8*)&hs[8];
    *(f16x8*)&sAl[sr][seg * 16] = *(f16x8*)&ls[0];
    *(f16x8*)&sAl[sr][seg * 16 + 8] = *(f16x8*)&ls[8];
    // --- stage B (already f16 ints) ---
    const f16x8* b8 = (const f16x8*)(bsrc + k0);
    *(f16x8*)&sB[sr][seg * 16] = b8[0];
    *(f16x8*)&sB[sr][seg * 16 + 8] = b8[1];
    __syncthreads();
    // --- MFMA ---
    f16x8 ah[4], al[4], bf[4];
    #pragma unroll
    for (int mi = 0; mi < 4; ++mi) {
      ah[mi] = *(const f16x8*)&sAh[wm + mi * 16 + row][kq * 8];
      al[mi] = *(const f16x8*)&sAl[wm + mi * 16 + row][kq * 8];
    }
    #pragma unroll
    for (int ni = 0; ni < 4; ++ni) bf[ni] = *(const f16x8*)&sB[wn + ni * 16 + row][kq * 8];
    #pragma unroll
    for (int mi = 0; mi < 4; ++mi)
      #pragma unroll
      for (int ni = 0; ni < 4; ++ni)
        acc[mi][ni] = __builtin_amdgcn_mfma_f32_16x16x32_f16(ah[mi], bf[ni], acc[mi][ni], 0, 0, 0);
    #pragma unroll
    for (int mi = 0; mi < 4; ++mi)
      #pragma unroll
      for (int ni = 0; ni < 4; ++ni)
        acc[mi][ni] = __builtin_amdgcn_mfma_f32_16x16x32_f16(al[mi], bf[ni], acc[mi][ni], 0, 0, 0);
  }
  // --- epilogue: scale + bias + lora, write k/v ---
  ((float2*)sT)[tid] = ((const float2*)(ttv + (size_t)m0 * 4))[tid];
  __syncthreads();
  float scale = __uint_as_float(absmax[mat]) * (1.0f / 7.0f);
  #pragma unroll
  for (int ni = 0; ni < 4; ++ni) {
    int nloc = wn + ni * 16 + row;
    int ncol = n0 + nloc;
    float4 lb = *(const float4*)(LBm + ncol * 4);
    float bias = qb[ncol];
    #pragma unroll
    for (int mi = 0; mi < 4; ++mi) {
      #pragma unroll
      for (int j = 0; j < 4; ++j) {
        int mloc = wm + mi * 16 + kq * 4 + j;
        float4 t4 = *(const float4*)&sT[mloc][0];
        float val = scale * acc[mi][ni][j] + bias +
                    4.0f * (t4.x * lb.x + t4.y * lb.y + t4.z * lb.z + t4.w * lb.w);
        outp[(size_t)(m0 + mloc) * 1024 + ncol] = (KVT)val;
      }
    }
  }
}

// ---------------- attention ----------------
template <typename KVT>
__device__ __forceinline__ float4 ld4(const KVT* p) {
  if constexpr (sizeof(KVT) == 4) {
    return *reinterpret_cast<const float4*>(p);
  } else {
    f16x4 v = *reinterpret_cast<const f16x4*>(p);
    return make_float4((float)v[0], (float)v[1], (float)v[2], (float)v[3]);
  }
}

template <typename KVT>
__global__ void __launch_bounds__(256) attn_kernel(
    const float* __restrict__ qbuf, const KVT* __restrict__ kbuf,
    const KVT* __restrict__ vbuf, const float* __restrict__ rel_bias,
    const int* __restrict__ curr_pos_p, float* __restrict__ attout) {
  __shared__ float sS[2048];
  __shared__ float red[8];
  __shared__ float sO[2][128];
  int bh = blockIdx.x;
  int b = bh >> 3, h = bh & 7;
  int tid = threadIdx.x, lane = tid & 63, wave = tid >> 6;
  int j4 = lane & 31, ph = lane >> 5;
  const float4 qv = *(const float4*)(qbuf + b * 1024 + h * 128 + j4 * 4);
  int off = *curr_pos_p - NP + 64;  // idx = clamp(p + off, 0, 128)
  for (int i = 0; i < 256; ++i) {
    int p = i * 8 + wave * 2 + ph;
    float4 kv = ld4(kbuf + ((size_t)(p * 16 + b)) * 1024 + h * 128 + j4 * 4);
    int idx = min(max(p + off, 0), 128);
    float4 rb = *(const float4*)(rel_bias + idx * 1024 + h * 128 + j4 * 4);
    float acc = qv.x * (kv.x + rb.x) + qv.y * (kv.y + rb.y) +
                qv.z * (kv.z + rb.z) + qv.w * (kv.w + rb.w);
    acc += __shfl_xor(acc, 16);
    acc += __shfl_xor(acc, 8);
    acc += __shfl_xor(acc, 4);
    acc += __shfl_xor(acc, 2);
    acc += __shfl_xor(acc, 1);
    if (j4 == 0) sS[p] = acc * 0.125f;  // 1/sqrt(64)
  }
  __syncthreads();
  float mx = -1e30f;
  for (int i = tid; i < 2048; i += 256) mx = fmaxf(mx, sS[i]);
  #pragma unroll
  for (int k = 32; k >= 1; k >>= 1) mx = fmaxf(mx, __shfl_xor(mx, k));
  if (lane == 0) red[wave] = mx;
  __syncthreads();
  mx = fmaxf(fmaxf(red[0], red[1]), fmaxf(red[2], red[3]));
  float sum = 0.f;
  for (int i = tid; i < 2048; i += 256) {
    float e = expf(sS[i] - mx);
    sS[i] = e;
    sum += e;
  }
  #pragma unroll
  for (int k = 32; k >= 1; k >>= 1) sum += __shfl_xor(sum, k);
  if (lane == 0) red[4 + wave] = sum;
  __syncthreads();
  float inv = 1.0f / (red[4] + red[5] + red[6] + red[7]);
  int j = tid & 127, s = tid >> 7;
  const KVT* vp = vbuf + (size_t)b * 1024 + h * 128 + j;
  float acc = 0.f;
  #pragma unroll 4
  for (int i = 0; i < 1024; ++i) {
    int p = s + 2 * i;
    acc += sS[p] * (float)vp[(size_t)p * 16384];
  }
  sO[s][j] = acc;
  __syncthreads();
  if (s == 0) attout[b * 1024 + h * 128 + j] = (sO[0][j] + sO[1][j]) * inv;
}

// ---------------- host launch ----------------
extern "C" void kernel_launch(void* const* d_in, const int* in_sizes, int n_in,
                              void* d_out, int out_size, void* d_ws, size_t ws_size,
                              hipStream_t stream) {
  const int* curr_pos = (const int*)d_in[0];
  const float* z_curr = (const float*)d_in[1];
  const float* z_past = (const float*)d_in[2];
  const float* rel_bias = (const float*)d_in[3];
  const float* Wq = (const float*)d_in[4];
  const float* bq = (const float*)d_in[5];
  const float* Aq = (const float*)d_in[6];
  const float* LBq = (const float*)d_in[7];
  const float* Wk = (const float*)d_in[8];
  const float* bk = (const float*)d_in[9];
  const float* Ak = (const float*)d_in[10];
  const float* LBk = (const float*)d_in[11];
  const float* Wv = (const float*)d_in[12];
  const float* bv = (const float*)d_in[13];
  const float* Av = (const float*)d_in[14];
  const float* LBv = (const float*)d_in[15];
  const float* Wo = (const float*)d_in[16];
  const float* bo = (const float*)d_in[17];
  const float* Ao = (const float*)d_in[18];
  const float* LBo = (const float*)d_in[19];

  char* ws = (char*)d_ws;
  unsigned* absmax = (unsigned*)(ws + OFF_ABSMAX);
  float* t_q = (float*)(ws + OFF_TQ);
  float* t_o = (float*)(ws + OFF_TO);
  float* qbias = (float*)(ws + OFF_QBIAS);
  f16* xqh = (f16*)(ws + OFF_XQH);
  f16* xql = (f16*)(ws + OFF_XQL);
  f16* xoh = (f16*)(ws + OFF_XOH);
  f16* xol = (f16*)(ws + OFF_XOL);
  float* qbuf = (float*)(ws + OFF_QBUF);
  float* attout = (float*)(ws + OFF_ATT);
  f16* Wh = (f16*)(ws + OFF_WH);
  float* t_k = (float*)(ws + OFF_TK);
  float* t_v = (float*)(ws + OFF_TV);
  char* kvbase = ws + OFF_KV;

  bool f32kv = ws_size >= (size_t)OFF_KV + 2ull * 134217728ull;

  hipMemsetAsync(absmax, 0, 16, stream);
  absmax_kernel<<<256, 256, 0, stream>>>(Wq, Wk, Wv, Wo, absmax);
  bias_quant_kernel<<<4, 256, 0, stream>>>(bq, bk, bv, bo, qbias);
  quantW_kernel<<<4096, 256, 0, stream>>>(Wq, Wk, Wv, Wo, absmax, Wh);
  cvt_hilo_kernel<<<16, 256, 0, stream>>>(z_curr, xqh, xql);
  lora_t_small_kernel<<<1, 256, 0, stream>>>(z_curr, Aq, t_q);
  gemv_mfma_kernel<<<16, 256, 0, stream>>>(xqh, xql, Wh, absmax, 0, qbias, t_q, LBq, qbuf);
  lora_t_big_kernel<<<2048, 256, 0, stream>>>(z_past, Ak, Av, t_k, t_v);
  if (f32kv) {
    float* kb = (float*)kvbase;
    float* vb = kb + (size_t)M_ROWS * 1024;
    kv_gemm_kernel<float><<<dim3(256, 16), 256, 0, stream>>>(
        z_past, Wh, absmax, qbias, t_k, t_v, LBk, LBv, kb, vb);
    attn_kernel<float><<<128, 256, 0, stream>>>(qbuf, kb, vb, rel_bias, curr_pos, attout);
  } else {
    f16* kb = (f16*)kvbase;
    f16* vb = kb + (size_t)M_ROWS * 1024;
    kv_gemm_kernel<f16><<<dim3(256, 16), 256, 0, stream>>>(
        z_past, Wh, absmax, qbias, t_k, t_v, LBk, LBv, kb, vb);
    attn_kernel<f16><<<128, 256, 0, stream>>>(qbuf, kb, vb, rel_bias, curr_pos, attout);
  }
  cvt_hilo_kernel<<<16, 256, 0, stream>>>(attout, xoh, xol);
  lora_t_small_kernel<<<1, 256, 0, stream>>>(attout, Ao, t_o);
  gemv_mfma_kernel<<<16, 256, 0, stream>>>(xoh, xol, Wh + 3ull * 1048576ull, absmax, 3,
                                           qbias + 3 * 1024, t_o, LBo, (float*)d_out);
}

// Round 2
// 875.418 us; speedup vs baseline: 1.1479x; 1.1479x over previous
//
#include <hip/hip_runtime.h>
#include <math.h>

typedef _Float16 f16;
typedef _Float16 f16x8 __attribute__((ext_vector_type(8)));
typedef _Float16 f16x4 __attribute__((ext_vector_type(4)));
typedef float f32x4 __attribute__((ext_vector_type(4)));

#define NP 2048
#define M_ROWS 32768

// ---------------- ws layout (bytes) ----------------
#define OFF_ABSMAX 0u
#define OFF_TQ     256u
#define OFF_TO     512u
#define OFF_QBIAS  1024u        // 4*1024 f32
#define OFF_XQH    32768u       // 16*1024 f16
#define OFF_XQL    65536u
#define OFF_XOH    98304u
#define OFF_XOL    131072u
#define OFF_QBUF   163840u      // 16*1024 f32
#define OFF_ATT    229376u      // 16*1024 f32 (ends 294912)
#define OFF_PM     294912u      // 1024 f32 attn partial max
#define OFF_PL     299008u      // 1024 f32 attn partial sum
#define OFF_PO     303104u      // 1024*128 f32 attn partial out (ends 827392)
#define OFF_WH     1048576u     // 4 * 1M f16 = 8 MB
#define OFF_TK     9437184u     // 32768*4 f32
#define OFF_TV     9961472u
#define OFF_KV     10485760u    // K,V buffers; then optional zph/zpl f16 hi/lo

__device__ __forceinline__ float qint_of(float w, float scale) {
    return fminf(7.f, fmaxf(-8.f, rintf(w / (scale + 1e-8f))));
}

__device__ __forceinline__ void gload16(const void* g, void* l) {
  __builtin_amdgcn_global_load_lds((const __attribute__((address_space(1))) void*)g,
                                   (__attribute__((address_space(3))) void*)l, 16, 0, 0);
}

// ---------------- absmax over 4 weight matrices ----------------
__global__ void __launch_bounds__(256) absmax_kernel(
    const float* __restrict__ W0, const float* __restrict__ W1,
    const float* __restrict__ W2, const float* __restrict__ W3,
    unsigned* __restrict__ absmax) {
  int mat = blockIdx.x >> 6;
  int blk = blockIdx.x & 63;
  const float* W = mat == 0 ? W0 : mat == 1 ? W1 : mat == 2 ? W2 : W3;
  int tid = blk * 256 + threadIdx.x;      // 0..16383
  const float4* W4 = (const float4*)W;
  float m = 0.f;
  #pragma unroll
  for (int i = 0; i < 16; ++i) {
    float4 v = W4[tid + i * 16384];
    m = fmaxf(m, fmaxf(fmaxf(fabsf(v.x), fabsf(v.y)), fmaxf(fabsf(v.z), fabsf(v.w))));
  }
  #pragma unroll
  for (int k = 32; k >= 1; k >>= 1) m = fmaxf(m, __shfl_xor(m, k));
  __shared__ float sm[4];
  if ((threadIdx.x & 63) == 0) sm[threadIdx.x >> 6] = m;
  __syncthreads();
  if (threadIdx.x == 0) {
    m = fmaxf(fmaxf(sm[0], sm[1]), fmaxf(sm[2], sm[3]));
    atomicMax(&absmax[mat], __float_as_uint(m));
  }
}

// ---------------- quantize biases (simq) ----------------
__global__ void __launch_bounds__(256) bias_quant_kernel(
    const float* __restrict__ b0, const float* __restrict__ b1,
    const float* __restrict__ b2, const float* __restrict__ b3,
    float* __restrict__ qbias) {
  int mat = blockIdx.x;
  const float* bb = mat == 0 ? b0 : mat == 1 ? b1 : mat == 2 ? b2 : b3;
  int t = threadIdx.x;
  float4 v = ((const float4*)bb)[t];
  float m = fmaxf(fmaxf(fabsf(v.x), fabsf(v.y)), fmaxf(fabsf(v.z), fabsf(v.w)));
  #pragma unroll
  for (int k = 32; k >= 1; k >>= 1) m = fmaxf(m, __shfl_xor(m, k));
  __shared__ float sm[4];
  if ((t & 63) == 0) sm[t >> 6] = m;
  __syncthreads();
  float M = fmaxf(fmaxf(sm[0], sm[1]), fmaxf(sm[2], sm[3]));
  float scale = M * (1.0f / 7.0f);
  float4 q;
  q.x = (M == 0.f) ? v.x : qint_of(v.x, scale) * scale;
  q.y = (M == 0.f) ? v.y : qint_of(v.y, scale) * scale;
  q.z = (M == 0.f) ? v.z : qint_of(v.z, scale) * scale;
  q.w = (M == 0.f) ? v.w : qint_of(v.w, scale) * scale;
  ((float4*)(qbias + mat * 1024))[t] = q;
}

// ---------------- quantize W -> f16 integer values ----------------
__global__ void __launch_bounds__(256) quantW_kernel(
    const float* __restrict__ W0, const float* __restrict__ W1,
    const float* __restrict__ W2, const float* __restrict__ W3,
    const unsigned* __restrict__ absmax, f16* __restrict__ Wh) {
  int gid = blockIdx.x * 256 + threadIdx.x;  // float4 units
  int mat = gid >> 18;
  int idx = gid & 262143;
  const float* W = mat == 0 ? W0 : mat == 1 ? W1 : mat == 2 ? W2 : W3;
  float scale = __uint_as_float(absmax[mat]) * (1.0f / 7.0f);
  float4 v = ((const float4*)W)[idx];
  f16x4 r;
  r[0] = (f16)qint_of(v.x, scale);
  r[1] = (f16)qint_of(v.y, scale);
  r[2] = (f16)qint_of(v.z, scale);
  r[3] = (f16)qint_of(v.w, scale);
  *(f16x4*)(Wh + (size_t)mat * 1048576 + (size_t)idx * 4) = r;
}

// ---------------- f32 -> f16 hi/lo split (16K elems) ----------------
__global__ void __launch_bounds__(256) cvt_hilo_kernel(
    const float* __restrict__ x, f16* __restrict__ hi, f16* __restrict__ lo) {
  int i = blockIdx.x * 256 + threadIdx.x;
  float4 v = ((const float4*)x)[i];
  f16 h0 = (f16)v.x, h1 = (f16)v.y, h2 = (f16)v.z, h3 = (f16)v.w;
  f16x4 hv = {h0, h1, h2, h3};
  f16x4 lv = {(f16)(v.x - (float)h0), (f16)(v.y - (float)h1),
              (f16)(v.z - (float)h2), (f16)(v.w - (float)h3)};
  *(f16x4*)(hi + (size_t)i * 4) = hv;
  *(f16x4*)(lo + (size_t)i * 4) = lv;
}

// ---------------- lora t for 16-row x: t[16][4] ----------------
__global__ void __launch_bounds__(256) lora_t_small_kernel(
    const float* __restrict__ x, const float* __restrict__ A, float* __restrict__ t) {
  int tt = threadIdx.x;
  int b = tt >> 4;
  int r = (tt >> 2) & 3;
  int s = tt & 3;
  const float4* xv = (const float4*)(x + b * 1024 + s * 256);
  const float4* av = (const float4*)(A + r * 1024 + s * 256);
  float acc = 0.f;
  #pragma unroll 4
  for (int i = 0; i < 64; ++i) {
    float4 a = xv[i], c = av[i];
    acc += a.x * c.x + a.y * c.y + a.z * c.z + a.w * c.w;
  }
  acc += __shfl_xor(acc, 1);
  acc += __shfl_xor(acc, 2);
  if (s == 0) t[b * 4 + r] = acc;
}

// ---------------- lora t for z_past + optional f16 hi/lo split ----------------
__global__ void __launch_bounds__(256) lora_t_big_kernel(
    const float* __restrict__ zp, const float* __restrict__ Ak,
    const float* __restrict__ Av, float* __restrict__ tk, float* __restrict__ tv,
    f16* __restrict__ zph, f16* __restrict__ zpl) {
  __shared__ float sA[8 * 1024];
  for (int i = 0; i < 8; ++i) {
    int f4 = threadIdx.x + i * 256;
    float4 v = (f4 < 1024) ? ((const float4*)Ak)[f4] : ((const float4*)Av)[f4 - 1024];
    ((float4*)sA)[f4] = v;
  }
  __syncthreads();
  int lane = threadIdx.x & 63, wave = threadIdx.x >> 6;
  for (int it = 0; it < 4; ++it) {
    int m = blockIdx.x * 16 + wave * 4 + it;
    const float4* xr = (const float4*)(zp + (size_t)m * 1024);
    float acc[8] = {0.f, 0.f, 0.f, 0.f, 0.f, 0.f, 0.f, 0.f};
    for (int c = lane; c < 256; c += 64) {
      float4 xv = xr[c];
      if (zph) {
        f16 h0 = (f16)xv.x, h1 = (f16)xv.y, h2 = (f16)xv.z, h3 = (f16)xv.w;
        f16x4 hv = {h0, h1, h2, h3};
        f16x4 lv = {(f16)(xv.x - (float)h0), (f16)(xv.y - (float)h1),
                    (f16)(xv.z - (float)h2), (f16)(xv.w - (float)h3)};
        *(f16x4*)(zph + (size_t)m * 1024 + c * 4) = hv;
        *(f16x4*)(zpl + (size_t)m * 1024 + c * 4) = lv;
      }
      #pragma unroll
      for (int r = 0; r < 8; ++r) {
        float4 a = ((const float4*)sA)[r * 256 + c];
        acc[r] += xv.x * a.x + xv.y * a.y + xv.z * a.z + xv.w * a.w;
      }
    }
    #pragma unroll
    for (int k = 32; k >= 1; k >>= 1) {
      #pragma unroll
      for (int r = 0; r < 8; ++r) acc[r] += __shfl_xor(acc[r], k);
    }
    if (lane == 0) {
      tk[m * 4 + 0] = acc[0]; tk[m * 4 + 1] = acc[1];
      tk[m * 4 + 2] = acc[2]; tk[m * 4 + 3] = acc[3];
      tv[m * 4 + 0] = acc[4]; tv[m * 4 + 1] = acc[5];
      tv[m * 4 + 2] = acc[6]; tv[m * 4 + 3] = acc[7];
    }
  }
}

// ---------------- MFMA GEMV (M=16) ----------------
__global__ void __launch_bounds__(256) gemv_mfma_kernel(
    const f16* __restrict__ xhi, const f16* __restrict__ xlo,
    const f16* __restrict__ Wm, const unsigned* __restrict__ absmax, int mat,
    const float* __restrict__ qb, const float* __restrict__ t,
    const float* __restrict__ LB, float* __restrict__ out) {
  int wave = threadIdx.x >> 6, lane = threadIdx.x & 63;
  int nf = blockIdx.x * 4 + wave;
  int n0 = nf * 16;
  int row = lane & 15, kq = lane >> 4;
  f32x4 acc = {0.f, 0.f, 0.f, 0.f};
  const f16* xh = xhi + row * 1024 + kq * 8;
  const f16* xl = xlo + row * 1024 + kq * 8;
  const f16* wp = Wm + (size_t)(n0 + row) * 1024 + kq * 8;
  #pragma unroll 4
  for (int k0 = 0; k0 < 1024; k0 += 32) {
    f16x8 ah = *(const f16x8*)(xh + k0);
    f16x8 al = *(const f16x8*)(xl + k0);
    f16x8 bb = *(const f16x8*)(wp + k0);
    acc = __builtin_amdgcn_mfma_f32_16x16x32_f16(ah, bb, acc, 0, 0, 0);
    acc = __builtin_amdgcn_mfma_f32_16x16x32_f16(al, bb, acc, 0, 0, 0);
  }
  float scale = __uint_as_float(absmax[mat]) * (1.0f / 7.0f);
  int col = n0 + row;
  float bias = qb[col];
  float4 lb = *(const float4*)(LB + col * 4);
  #pragma unroll
  for (int j = 0; j < 4; ++j) {
    int m = kq * 4 + j;
    float4 tvv = *(const float4*)(t + m * 4);
    out[m * 1024 + col] =
        scale * acc[j] + bias + 4.0f * (tvv.x * lb.x + tvv.y * lb.y + tvv.z * lb.z + tvv.w * lb.w);
  }
}

// ---------------- legacy fused K+V GEMM (reg-staged; transposed epilogue) ----
template <typename KVT>
__global__ void __launch_bounds__(256, 2) kv_gemm_kernel(
    const float* __restrict__ zp, const f16* __restrict__ Wh,
    const unsigned* __restrict__ absmax, const float* __restrict__ qbias,
    const float* __restrict__ tk, const float* __restrict__ tv,
    const float* __restrict__ LBk, const float* __restrict__ LBv,
    KVT* __restrict__ kout, KVT* __restrict__ vout) {
  __shared__ __align__(16) f16 sAh[128][40];
  __shared__ __align__(16) f16 sAl[128][40];
  __shared__ __align__(16) f16 sB[128][40];
  __shared__ float sT[128][4];

  int nb = blockIdx.x;
  int m0 = blockIdx.y * 128;
  bool is_v = nb >= 8;
  int n0 = (nb & 7) * 128;
  int mat = is_v ? 2 : 1;
  const f16* Wm = Wh + (size_t)mat * 1048576;
  const float* ttv = is_v ? tv : tk;
  const float* LBm = is_v ? LBv : LBk;
  const float* qb = qbias + mat * 1024;
  KVT* outp = is_v ? vout : kout;

  int tid = threadIdx.x;
  int lane = tid & 63, wave = tid >> 6;
  int wm = (wave >> 1) * 64, wn = (wave & 1) * 64;
  int row = lane & 15, kq = lane >> 4;

  f32x4 acc[4][4];
  #pragma unroll
  for (int i = 0; i < 4; ++i)
    #pragma unroll
    for (int j = 0; j < 4; ++j) acc[i][j] = (f32x4){0.f, 0.f, 0.f, 0.f};

  int sr = tid >> 1, seg = tid & 1;
  const float* asrc = zp + (size_t)(m0 + sr) * 1024 + seg * 16;
  const f16* bsrc = Wm + (size_t)(n0 + sr) * 1024 + seg * 16;

  for (int k0 = 0; k0 < 1024; k0 += 32) {
    __syncthreads();
    float xs[16];
    const float4* a4 = (const float4*)(asrc + k0);
    *(float4*)&xs[0] = a4[0];
    *(float4*)&xs[4] = a4[1];
    *(float4*)&xs[8] = a4[2];
    *(float4*)&xs[12] = a4[3];
    f16 hs[16], ls[16];
    #pragma unroll
    for (int i = 0; i < 16; ++i) {
      f16 h = (f16)xs[i];
      hs[i] = h;
      ls[i] = (f16)(xs[i] - (float)h);
    }
    *(f16x8*)&sAh[sr][seg * 16] = *(f16x8*)&hs[0];
    *(f16x8*)&sAh[sr][seg * 16 + 8] = *(f16x8*)&hs[8];
    *(f16x8*)&sAl[sr][seg * 16] = *(f16x8*)&ls[0];
    *(f16x8*)&sAl[sr][seg * 16 + 8] = *(f16x8*)&ls[8];
    const f16x8* b8 = (const f16x8*)(bsrc + k0);
    *(f16x8*)&sB[sr][seg * 16] = b8[0];
    *(f16x8*)&sB[sr][seg * 16 + 8] = b8[1];
    __syncthreads();
    f16x8 ah[4], al[4], bf[4];
    #pragma unroll
    for (int mi = 0; mi < 4; ++mi) {
      ah[mi] = *(const f16x8*)&sAh[wm + mi * 16 + row][kq * 8];
      al[mi] = *(const f16x8*)&sAl[wm + mi * 16 + row][kq * 8];
    }
    #pragma unroll
    for (int ni = 0; ni < 4; ++ni) bf[ni] = *(const f16x8*)&sB[wn + ni * 16 + row][kq * 8];
    #pragma unroll
    for (int mi = 0; mi < 4; ++mi)
      #pragma unroll
      for (int ni = 0; ni < 4; ++ni)
        acc[mi][ni] = __builtin_amdgcn_mfma_f32_16x16x32_f16(ah[mi], bf[ni], acc[mi][ni], 0, 0, 0);
    #pragma unroll
    for (int mi = 0; mi < 4; ++mi)
      #pragma unroll
      for (int ni = 0; ni < 4; ++ni)
        acc[mi][ni] = __builtin_amdgcn_mfma_f32_16x16x32_f16(al[mi], bf[ni], acc[mi][ni], 0, 0, 0);
  }
  ((float2*)sT)[tid] = ((const float2*)(ttv + (size_t)m0 * 4))[tid];
  __syncthreads();
  float scale = __uint_as_float(absmax[mat]) * (1.0f / 7.0f);
  #pragma unroll
  for (int ni = 0; ni < 4; ++ni) {
    int ncol = n0 + wn + ni * 16 + row;
    int h = ncol >> 7, d = ncol & 127;
    float4 lb = *(const float4*)(LBm + ncol * 4);
    float bias = qb[ncol];
    #pragma unroll
    for (int mi = 0; mi < 4; ++mi) {
      #pragma unroll
      for (int j = 0; j < 4; ++j) {
        int mloc = wm + mi * 16 + kq * 4 + j;
        int m = m0 + mloc;
        int p = m >> 4, b = m & 15;
        float4 t4 = *(const float4*)&sT[mloc][0];
        float val = scale * acc[mi][ni][j] + bias +
                    4.0f * (t4.x * lb.x + t4.y * lb.y + t4.z * lb.z + t4.w * lb.w);
        outp[(((size_t)(b * 8 + h)) * 2048 + p) * 128 + d] = (KVT)val;
      }
    }
  }
}

// ---------------- fast fused K+V GEMM (global_load_lds, f16 hi/lo inputs) ----
template <typename KVT>
__global__ void __launch_bounds__(256, 3) kv_gemm_fast_kernel(
    const f16* __restrict__ zph, const f16* __restrict__ zpl,
    const f16* __restrict__ Wh, const unsigned* __restrict__ absmax,
    const float* __restrict__ qbias, const float* __restrict__ tk,
    const float* __restrict__ tv, const float* __restrict__ LBk,
    const float* __restrict__ LBv, KVT* __restrict__ kout, KVT* __restrict__ vout) {
  // [128 rows][64 k] f16, linear; content swizzled: chunk c' holds logical
  // chunk c'^(row&7). Source pre-swizzle + read swizzle (rule 21).
  __shared__ __align__(16) f16 sAh[8192];
  __shared__ __align__(16) f16 sAl[8192];
  __shared__ __align__(16) f16 sB[8192];
  __shared__ float sT[128][4];

  int nb = blockIdx.x;
  int m0 = blockIdx.y * 128;
  bool is_v = nb >= 8;
  int n0 = (nb & 7) * 128;
  int mat = is_v ? 2 : 1;
  const f16* Wm = Wh + (size_t)mat * 1048576;
  const float* ttv = is_v ? tv : tk;
  const float* LBm = is_v ? LBv : LBk;
  const float* qb = qbias + mat * 1024;
  KVT* outp = is_v ? vout : kout;

  int tid = threadIdx.x;
  int lane = tid & 63, wave = tid >> 6;
  int wm = (wave >> 1) * 64, wn = (wave & 1) * 64;
  int row = lane & 15, kq = lane >> 4;

  const f16* srcAh = zph + (size_t)m0 * 1024;
  const f16* srcAl = zpl + (size_t)m0 * 1024;
  const f16* srcB = Wm + (size_t)n0 * 1024;

  // staging geometry: 1024 16B-chunks/buffer, 4 rounds of 256 threads
  int goff[4], lbase[4];
  #pragma unroll
  for (int r = 0; r < 4; ++r) {
    int L = r * 256 + tid;
    int rw = L >> 3, cc = L & 7, cs = cc ^ (rw & 7);
    goff[r] = rw * 1024 + cs * 8;        // f16 elements (k0 added in loop)
    lbase[r] = (r * 256 + (wave << 6)) * 8;  // wave-uniform f16 index
  }

  f32x4 acc[4][4];
  #pragma unroll
  for (int i = 0; i < 4; ++i)
    #pragma unroll
    for (int j = 0; j < 4; ++j) acc[i][j] = (f32x4){0.f, 0.f, 0.f, 0.f};

  for (int k0 = 0; k0 < 1024; k0 += 64) {
    __syncthreads();
    #pragma unroll
    for (int r = 0; r < 4; ++r) {
      gload16(srcAh + goff[r] + k0, sAh + lbase[r]);
      gload16(srcAl + goff[r] + k0, sAl + lbase[r]);
      gload16(srcB + goff[r] + k0, sB + lbase[r]);
    }
    __syncthreads();  // compiler adds vmcnt(0) drain before barrier
    #pragma unroll
    for (int ks = 0; ks < 2; ++ks) {
      int ch = (ks * 4 + kq) ^ (row & 7);
      f16x8 ah[4], al[4], bf[4];
      #pragma unroll
      for (int mi = 0; mi < 4; ++mi) {
        int ad = (wm + mi * 16 + row) * 64 + ch * 8;
        ah[mi] = *(const f16x8*)&sAh[ad];
        al[mi] = *(const f16x8*)&sAl[ad];
      }
      #pragma unroll
      for (int ni = 0; ni < 4; ++ni)
        bf[ni] = *(const f16x8*)&sB[(wn + ni * 16 + row) * 64 + ch * 8];
      #pragma unroll
      for (int mi = 0; mi < 4; ++mi)
        #pragma unroll
        for (int ni = 0; ni < 4; ++ni)
          acc[mi][ni] = __builtin_amdgcn_mfma_f32_16x16x32_f16(ah[mi], bf[ni], acc[mi][ni], 0, 0, 0);
      #pragma unroll
      for (int mi = 0; mi < 4; ++mi)
        #pragma unroll
        for (int ni = 0; ni < 4; ++ni)
          acc[mi][ni] = __builtin_amdgcn_mfma_f32_16x16x32_f16(al[mi], bf[ni], acc[mi][ni], 0, 0, 0);
    }
  }
  ((float2*)sT)[tid] = ((const float2*)(ttv + (size_t)m0 * 4))[tid];
  __syncthreads();
  float scale = __uint_as_float(absmax[mat]) * (1.0f / 7.0f);
  #pragma unroll
  for (int ni = 0; ni < 4; ++ni) {
    int ncol = n0 + wn + ni * 16 + row;
    int h = ncol >> 7, d = ncol & 127;
    float4 lb = *(const float4*)(LBm + ncol * 4);
    float bias = qb[ncol];
    #pragma unroll
    for (int mi = 0; mi < 4; ++mi) {
      #pragma unroll
      for (int j = 0; j < 4; ++j) {
        int mloc = wm + mi * 16 + kq * 4 + j;
        int m = m0 + mloc;
        int p = m >> 4, b = m & 15;
        float4 t4 = *(const float4*)&sT[mloc][0];
        float val = scale * acc[mi][ni][j] + bias +
                    4.0f * (t4.x * lb.x + t4.y * lb.y + t4.z * lb.z + t4.w * lb.w);
        outp[(((size_t)(b * 8 + h)) * 2048 + p) * 128 + d] = (KVT)val;
      }
    }
  }
}

// ---------------- attention (split-P flash over [BH][P][128] KV) ----------
template <typename KVT>
__device__ __forceinline__ float4 ld4(const KVT* p) {
  if constexpr (sizeof(KVT) == 4) {
    return *reinterpret_cast<const float4*>(p);
  } else {
    f16x4 v = *reinterpret_cast<const f16x4*>(p);
    return make_float4((float)v[0], (float)v[1], (float)v[2], (float)v[3]);
  }
}

template <typename KVT>
__global__ void __launch_bounds__(256) attn_part_kernel(
    const float* __restrict__ qbuf, const KVT* __restrict__ kbuf,
    const KVT* __restrict__ vbuf, const float* __restrict__ rel_bias,
    const int* __restrict__ curr_pos_p, float* __restrict__ m_part,
    float* __restrict__ l_part, float* __restrict__ o_part) {
  __shared__ float sS[256];
  __shared__ float red[8];
  __shared__ float sO[2][128];
  int bh = blockIdx.x;            // b*8+h
  int c = blockIdx.y;             // P chunk
  int b = bh >> 3, h = bh & 7;
  int p0 = c * 256;
  int tid = threadIdx.x, lane = tid & 63, wave = tid >> 6;
  int j4 = lane & 31, ph = lane >> 5;
  float4 qv = *(const float4*)(qbuf + b * 1024 + h * 128 + j4 * 4);
  int off = *curr_pos_p - NP + 64;
  const KVT* kb = kbuf + ((size_t)bh * 2048 + p0) * 128;
  for (int i = 0; i < 32; ++i) {
    int pl = i * 8 + wave * 2 + ph;
    float4 kv = ld4(kb + (size_t)pl * 128 + j4 * 4);
    int idx = min(max(p0 + pl + off, 0), 128);
    float4 rb = *(const float4*)(rel_bias + idx * 1024 + h * 128 + j4 * 4);
    float a = qv.x * (kv.x + rb.x) + qv.y * (kv.y + rb.y) +
              qv.z * (kv.z + rb.z) + qv.w * (kv.w + rb.w);
    a += __shfl_xor(a, 16);
    a += __shfl_xor(a, 8);
    a += __shfl_xor(a, 4);
    a += __shfl_xor(a, 2);
    a += __shfl_xor(a, 1);
    if (j4 == 0) sS[pl] = a * 0.125f;  // 1/sqrt(64)
  }
  __syncthreads();
  float v = sS[tid];
  float mx = v;
  #pragma unroll
  for (int k = 32; k >= 1; k >>= 1) mx = fmaxf(mx, __shfl_xor(mx, k));
  if (lane == 0) red[wave] = mx;
  __syncthreads();
  mx = fmaxf(fmaxf(red[0], red[1]), fmaxf(red[2], red[3]));
  float e = expf(v - mx);
  sS[tid] = e;
  float sum = e;
  #pragma unroll
  for (int k = 32; k >= 1; k >>= 1) sum += __shfl_xor(sum, k);
  if (lane == 0) red[4 + wave] = sum;
  __syncthreads();
  float l = red[4] + red[5] + red[6] + red[7];
  // PV: group s handles 128 consecutive p's
  int d = tid & 127, s = tid >> 7;
  const KVT* vb = vbuf + ((size_t)bh * 2048 + p0 + s * 128) * 128 + d;
  float acc = 0.f;
  #pragma unroll 4
  for (int i = 0; i < 128; ++i) acc += sS[s * 128 + i] * (float)vb[(size_t)i * 128];
  sO[s][d] = acc;
  __syncthreads();
  if (s == 0) {
    int pc = bh * 8 + c;
    o_part[pc * 128 + d] = sO[0][d] + sO[1][d];
    if (d == 0) {
      m_part[pc] = mx;
      l_part[pc] = l;
    }
  }
}

__global__ void __launch_bounds__(128) attn_combine_kernel(
    const float* __restrict__ m_part, const float* __restrict__ l_part,
    const float* __restrict__ o_part, float* __restrict__ attout) {
  int bh = blockIdx.x;
  int d = threadIdx.x;
  float M = -1e30f;
  #pragma unroll
  for (int c = 0; c < 8; ++c) M = fmaxf(M, m_part[bh * 8 + c]);
  float L = 0.f, o = 0.f;
  #pragma unroll
  for (int c = 0; c < 8; ++c) {
    float w = expf(m_part[bh * 8 + c] - M);
    L += w * l_part[bh * 8 + c];
    o += w * o_part[(bh * 8 + c) * 128 + d];
  }
  int b = bh >> 3, h = bh & 7;
  attout[b * 1024 + h * 128 + d] = o / L;
}

// ---------------- host launch ----------------
extern "C" void kernel_launch(void* const* d_in, const int* in_sizes, int n_in,
                              void* d_out, int out_size, void* d_ws, size_t ws_size,
                              hipStream_t stream) {
  const int* curr_pos = (const int*)d_in[0];
  const float* z_curr = (const float*)d_in[1];
  const float* z_past = (const float*)d_in[2];
  const float* rel_bias = (const float*)d_in[3];
  const float* Wq = (const float*)d_in[4];
  const float* bq = (const float*)d_in[5];
  const float* Aq = (const float*)d_in[6];
  const float* LBq = (const float*)d_in[7];
  const float* Wk = (const float*)d_in[8];
  const float* bk = (const float*)d_in[9];
  const float* Ak = (const float*)d_in[10];
  const float* LBk = (const float*)d_in[11];
  const float* Wv = (const float*)d_in[12];
  const float* bv = (const float*)d_in[13];
  const float* Av = (const float*)d_in[14];
  const float* LBv = (const float*)d_in[15];
  const float* Wo = (const float*)d_in[16];
  const float* bo = (const float*)d_in[17];
  const float* Ao = (const float*)d_in[18];
  const float* LBo = (const float*)d_in[19];

  char* ws = (char*)d_ws;
  unsigned* absmax = (unsigned*)(ws + OFF_ABSMAX);
  float* t_q = (float*)(ws + OFF_TQ);
  float* t_o = (float*)(ws + OFF_TO);
  float* qbias = (float*)(ws + OFF_QBIAS);
  f16* xqh = (f16*)(ws + OFF_XQH);
  f16* xql = (f16*)(ws + OFF_XQL);
  f16* xoh = (f16*)(ws + OFF_XOH);
  f16* xol = (f16*)(ws + OFF_XOL);
  float* qbuf = (float*)(ws + OFF_QBUF);
  float* attout = (float*)(ws + OFF_ATT);
  float* pm = (float*)(ws + OFF_PM);
  float* pl = (float*)(ws + OFF_PL);
  float* po = (float*)(ws + OFF_PO);
  f16* Wh = (f16*)(ws + OFF_WH);
  float* t_k = (float*)(ws + OFF_TK);
  float* t_v = (float*)(ws + OFF_TV);
  char* kvbase = ws + OFF_KV;

  bool f32kv = ws_size >= (size_t)OFF_KV + 2ull * 134217728ull;
  size_t kvBytes1 = f32kv ? 134217728ull : 67108864ull;
  f16* zph = (f16*)(kvbase + 2 * kvBytes1);
  f16* zpl = (f16*)(kvbase + 2 * kvBytes1 + 67108864ull);
  bool fast = ws_size >= (size_t)OFF_KV + 2 * kvBytes1 + 2ull * 67108864ull;

  hipMemsetAsync(absmax, 0, 16, stream);
  absmax_kernel<<<256, 256, 0, stream>>>(Wq, Wk, Wv, Wo, absmax);
  bias_quant_kernel<<<4, 256, 0, stream>>>(bq, bk, bv, bo, qbias);
  quantW_kernel<<<4096, 256, 0, stream>>>(Wq, Wk, Wv, Wo, absmax, Wh);
  cvt_hilo_kernel<<<16, 256, 0, stream>>>(z_curr, xqh, xql);
  lora_t_small_kernel<<<1, 256, 0, stream>>>(z_curr, Aq, t_q);
  gemv_mfma_kernel<<<16, 256, 0, stream>>>(xqh, xql, Wh, absmax, 0, qbias, t_q, LBq, qbuf);
  lora_t_big_kernel<<<2048, 256, 0, stream>>>(z_past, Ak, Av, t_k, t_v,
                                              fast ? zph : nullptr, fast ? zpl : nullptr);
  if (f32kv) {
    float* kb = (float*)kvbase;
    float* vb = (float*)(kvbase + kvBytes1);
    if (fast)
      kv_gemm_fast_kernel<float><<<dim3(16, 256), 256, 0, stream>>>(
          zph, zpl, Wh, absmax, qbias, t_k, t_v, LBk, LBv, kb, vb);
    else
      kv_gemm_kernel<float><<<dim3(16, 256), 256, 0, stream>>>(
          z_past, Wh, absmax, qbias, t_k, t_v, LBk, LBv, kb, vb);
    attn_part_kernel<float><<<dim3(128, 8), 256, 0, stream>>>(
        qbuf, kb, vb, rel_bias, curr_pos, pm, pl, po);
  } else {
    f16* kb = (f16*)kvbase;
    f16* vb = (f16*)(kvbase + kvBytes1);
    if (fast)
      kv_gemm_fast_kernel<f16><<<dim3(16, 256), 256, 0, stream>>>(
          zph, zpl, Wh, absmax, qbias, t_k, t_v, LBk, LBv, kb, vb);
    else
      kv_gemm_kernel<f16><<<dim3(16, 256), 256, 0, stream>>>(
          z_past, Wh, absmax, qbias, t_k, t_v, LBk, LBv, kb, vb);
    attn_part_kernel<f16><<<dim3(128, 8), 256, 0, stream>>>(
        qbuf, kb, vb, rel_bias, curr_pos, pm, pl, po);
  }
  attn_combine_kernel<<<128, 128, 0, stream>>>(pm, pl, po, attout);
  cvt_hilo_kernel<<<16, 256, 0, stream>>>(attout, xoh, xol);
  lora_t_small_kernel<<<1, 256, 0, stream>>>(attout, Ao, t_o);
  gemv_mfma_kernel<<<16, 256, 0, stream>>>(xoh, xol, Wh + 3ull * 1048576ull, absmax, 3,
                                           qbias + 3 * 1024, t_o, LBo, (float*)d_out);
}

// Round 3
// 827.149 us; speedup vs baseline: 1.2148x; 1.0584x over previous
//
#include <hip/hip_runtime.h>
#include <math.h>

typedef _Float16 f16;
typedef _Float16 f16x8 __attribute__((ext_vector_type(8)));
typedef _Float16 f16x4 __attribute__((ext_vector_type(4)));
typedef float f32x4 __attribute__((ext_vector_type(4)));

#define NP 2048
#define M_ROWS 32768

// ---------------- ws layout (bytes) ----------------
#define OFF_ABSMAX 0u
#define OFF_TQ     256u
#define OFF_TO     512u
#define OFF_QBIAS  1024u        // 4*1024 f32
#define OFF_XQH    32768u       // 16*1024 f16
#define OFF_XQL    65536u
#define OFF_XOH    98304u
#define OFF_XOL    131072u
#define OFF_QBUF   163840u      // 16*1024 f32
#define OFF_ATT    229376u      // 16*1024 f32 (ends 294912)
#define OFF_PM     294912u      // 1024 f32 attn partial max
#define OFF_PL     299008u      // 1024 f32 attn partial sum
#define OFF_PO     303104u      // 1024*128 f32 attn partial out (ends 827392)
#define OFF_WH     1048576u     // 4 * 1M f16 = 8 MB
#define OFF_TK     9437184u     // 32768*4 f32
#define OFF_TV     9961472u
#define OFF_KV     10485760u    // K,V buffers; then optional zph/zpl f16 hi/lo

__device__ __forceinline__ float qint_of(float w, float scale) {
    return fminf(7.f, fmaxf(-8.f, rintf(w / (scale + 1e-8f))));
}

__device__ __forceinline__ void gload16(const void* g, void* l) {
  __builtin_amdgcn_global_load_lds((const __attribute__((address_space(1))) void*)g,
                                   (__attribute__((address_space(3))) void*)l, 16, 0, 0);
}

// ---------------- absmax over 4 weight matrices ----------------
__global__ void __launch_bounds__(256) absmax_kernel(
    const float* __restrict__ W0, const float* __restrict__ W1,
    const float* __restrict__ W2, const float* __restrict__ W3,
    unsigned* __restrict__ absmax) {
  int mat = blockIdx.x >> 6;
  int blk = blockIdx.x & 63;
  const float* W = mat == 0 ? W0 : mat == 1 ? W1 : mat == 2 ? W2 : W3;
  int tid = blk * 256 + threadIdx.x;      // 0..16383
  const float4* W4 = (const float4*)W;
  float m = 0.f;
  #pragma unroll
  for (int i = 0; i < 16; ++i) {
    float4 v = W4[tid + i * 16384];
    m = fmaxf(m, fmaxf(fmaxf(fabsf(v.x), fabsf(v.y)), fmaxf(fabsf(v.z), fabsf(v.w))));
  }
  #pragma unroll
  for (int k = 32; k >= 1; k >>= 1) m = fmaxf(m, __shfl_xor(m, k));
  __shared__ float sm[4];
  if ((threadIdx.x & 63) == 0) sm[threadIdx.x >> 6] = m;
  __syncthreads();
  if (threadIdx.x == 0) {
    m = fmaxf(fmaxf(sm[0], sm[1]), fmaxf(sm[2], sm[3]));
    atomicMax(&absmax[mat], __float_as_uint(m));
  }
}

// ---------------- quantize biases (simq) ----------------
__global__ void __launch_bounds__(256) bias_quant_kernel(
    const float* __restrict__ b0, const float* __restrict__ b1,
    const float* __restrict__ b2, const float* __restrict__ b3,
    float* __restrict__ qbias) {
  int mat = blockIdx.x;
  const float* bb = mat == 0 ? b0 : mat == 1 ? b1 : mat == 2 ? b2 : b3;
  int t = threadIdx.x;
  float4 v = ((const float4*)bb)[t];
  float m = fmaxf(fmaxf(fabsf(v.x), fabsf(v.y)), fmaxf(fabsf(v.z), fabsf(v.w)));
  #pragma unroll
  for (int k = 32; k >= 1; k >>= 1) m = fmaxf(m, __shfl_xor(m, k));
  __shared__ float sm[4];
  if ((t & 63) == 0) sm[t >> 6] = m;
  __syncthreads();
  float M = fmaxf(fmaxf(sm[0], sm[1]), fmaxf(sm[2], sm[3]));
  float scale = M * (1.0f / 7.0f);
  float4 q;
  q.x = (M == 0.f) ? v.x : qint_of(v.x, scale) * scale;
  q.y = (M == 0.f) ? v.y : qint_of(v.y, scale) * scale;
  q.z = (M == 0.f) ? v.z : qint_of(v.z, scale) * scale;
  q.w = (M == 0.f) ? v.w : qint_of(v.w, scale) * scale;
  ((float4*)(qbias + mat * 1024))[t] = q;
}

// ---------------- quantize W -> f16 integer values ----------------
__global__ void __launch_bounds__(256) quantW_kernel(
    const float* __restrict__ W0, const float* __restrict__ W1,
    const float* __restrict__ W2, const float* __restrict__ W3,
    const unsigned* __restrict__ absmax, f16* __restrict__ Wh) {
  int gid = blockIdx.x * 256 + threadIdx.x;  // float4 units
  int mat = gid >> 18;
  int idx = gid & 262143;
  const float* W = mat == 0 ? W0 : mat == 1 ? W1 : mat == 2 ? W2 : W3;
  float scale = __uint_as_float(absmax[mat]) * (1.0f / 7.0f);
  float4 v = ((const float4*)W)[idx];
  f16x4 r;
  r[0] = (f16)qint_of(v.x, scale);
  r[1] = (f16)qint_of(v.y, scale);
  r[2] = (f16)qint_of(v.z, scale);
  r[3] = (f16)qint_of(v.w, scale);
  *(f16x4*)(Wh + (size_t)mat * 1048576 + (size_t)idx * 4) = r;
}

// ---------------- f32 -> f16 hi/lo split (16K elems) ----------------
__global__ void __launch_bounds__(256) cvt_hilo_kernel(
    const float* __restrict__ x, f16* __restrict__ hi, f16* __restrict__ lo) {
  int i = blockIdx.x * 256 + threadIdx.x;
  float4 v = ((const float4*)x)[i];
  f16 h0 = (f16)v.x, h1 = (f16)v.y, h2 = (f16)v.z, h3 = (f16)v.w;
  f16x4 hv = {h0, h1, h2, h3};
  f16x4 lv = {(f16)(v.x - (float)h0), (f16)(v.y - (float)h1),
              (f16)(v.z - (float)h2), (f16)(v.w - (float)h3)};
  *(f16x4*)(hi + (size_t)i * 4) = hv;
  *(f16x4*)(lo + (size_t)i * 4) = lv;
}

// ---------------- lora t for 16-row x: t[16][4] ----------------
__global__ void __launch_bounds__(256) lora_t_small_kernel(
    const float* __restrict__ x, const float* __restrict__ A, float* __restrict__ t) {
  int tt = threadIdx.x;
  int b = tt >> 4;
  int r = (tt >> 2) & 3;
  int s = tt & 3;
  const float4* xv = (const float4*)(x + b * 1024 + s * 256);
  const float4* av = (const float4*)(A + r * 1024 + s * 256);
  float acc = 0.f;
  #pragma unroll 4
  for (int i = 0; i < 64; ++i) {
    float4 a = xv[i], c = av[i];
    acc += a.x * c.x + a.y * c.y + a.z * c.z + a.w * c.w;
  }
  acc += __shfl_xor(acc, 1);
  acc += __shfl_xor(acc, 2);
  if (s == 0) t[b * 4 + r] = acc;
}

// ---------------- lora t for z_past + optional f16 hi/lo split ----------------
__global__ void __launch_bounds__(256) lora_t_big_kernel(
    const float* __restrict__ zp, const float* __restrict__ Ak,
    const float* __restrict__ Av, float* __restrict__ tk, float* __restrict__ tv,
    f16* __restrict__ zph, f16* __restrict__ zpl) {
  __shared__ float sA[8 * 1024];
  for (int i = 0; i < 8; ++i) {
    int f4 = threadIdx.x + i * 256;
    float4 v = (f4 < 1024) ? ((const float4*)Ak)[f4] : ((const float4*)Av)[f4 - 1024];
    ((float4*)sA)[f4] = v;
  }
  __syncthreads();
  int lane = threadIdx.x & 63, wave = threadIdx.x >> 6;
  for (int it = 0; it < 4; ++it) {
    int m = blockIdx.x * 16 + wave * 4 + it;
    const float4* xr = (const float4*)(zp + (size_t)m * 1024);
    float acc[8] = {0.f, 0.f, 0.f, 0.f, 0.f, 0.f, 0.f, 0.f};
    for (int c = lane; c < 256; c += 64) {
      float4 xv = xr[c];
      if (zph) {
        f16 h0 = (f16)xv.x, h1 = (f16)xv.y, h2 = (f16)xv.z, h3 = (f16)xv.w;
        f16x4 hv = {h0, h1, h2, h3};
        f16x4 lv = {(f16)(xv.x - (float)h0), (f16)(xv.y - (float)h1),
                    (f16)(xv.z - (float)h2), (f16)(xv.w - (float)h3)};
        *(f16x4*)(zph + (size_t)m * 1024 + c * 4) = hv;
        *(f16x4*)(zpl + (size_t)m * 1024 + c * 4) = lv;
      }
      #pragma unroll
      for (int r = 0; r < 8; ++r) {
        float4 a = ((const float4*)sA)[r * 256 + c];
        acc[r] += xv.x * a.x + xv.y * a.y + xv.z * a.z + xv.w * a.w;
      }
    }
    #pragma unroll
    for (int k = 32; k >= 1; k >>= 1) {
      #pragma unroll
      for (int r = 0; r < 8; ++r) acc[r] += __shfl_xor(acc[r], k);
    }
    if (lane == 0) {
      tk[m * 4 + 0] = acc[0]; tk[m * 4 + 1] = acc[1];
      tk[m * 4 + 2] = acc[2]; tk[m * 4 + 3] = acc[3];
      tv[m * 4 + 0] = acc[4]; tv[m * 4 + 1] = acc[5];
      tv[m * 4 + 2] = acc[6]; tv[m * 4 + 3] = acc[7];
    }
  }
}

// ---------------- MFMA GEMV (M=16) ----------------
__global__ void __launch_bounds__(256) gemv_mfma_kernel(
    const f16* __restrict__ xhi, const f16* __restrict__ xlo,
    const f16* __restrict__ Wm, const unsigned* __restrict__ absmax, int mat,
    const float* __restrict__ qb, const float* __restrict__ t,
    const float* __restrict__ LB, float* __restrict__ out) {
  int wave = threadIdx.x >> 6, lane = threadIdx.x & 63;
  int nf = blockIdx.x * 4 + wave;
  int n0 = nf * 16;
  int row = lane & 15, kq = lane >> 4;
  f32x4 acc = {0.f, 0.f, 0.f, 0.f};
  const f16* xh = xhi + row * 1024 + kq * 8;
  const f16* xl = xlo + row * 1024 + kq * 8;
  const f16* wp = Wm + (size_t)(n0 + row) * 1024 + kq * 8;
  #pragma unroll 4
  for (int k0 = 0; k0 < 1024; k0 += 32) {
    f16x8 ah = *(const f16x8*)(xh + k0);
    f16x8 al = *(const f16x8*)(xl + k0);
    f16x8 bb = *(const f16x8*)(wp + k0);
    acc = __builtin_amdgcn_mfma_f32_16x16x32_f16(ah, bb, acc, 0, 0, 0);
    acc = __builtin_amdgcn_mfma_f32_16x16x32_f16(al, bb, acc, 0, 0, 0);
  }
  float scale = __uint_as_float(absmax[mat]) * (1.0f / 7.0f);
  int col = n0 + row;
  float bias = qb[col];
  float4 lb = *(const float4*)(LB + col * 4);
  #pragma unroll
  for (int j = 0; j < 4; ++j) {
    int m = kq * 4 + j;
    float4 tvv = *(const float4*)(t + m * 4);
    out[m * 1024 + col] =
        scale * acc[j] + bias + 4.0f * (tvv.x * lb.x + tvv.y * lb.y + tvv.z * lb.z + tvv.w * lb.w);
  }
}

// ---------------- legacy fused K+V GEMM (reg-staged; transposed epilogue) ----
template <typename KVT>
__global__ void __launch_bounds__(256, 2) kv_gemm_kernel(
    const float* __restrict__ zp, const f16* __restrict__ Wh,
    const unsigned* __restrict__ absmax, const float* __restrict__ qbias,
    const float* __restrict__ tk, const float* __restrict__ tv,
    const float* __restrict__ LBk, const float* __restrict__ LBv,
    KVT* __restrict__ kout, KVT* __restrict__ vout) {
  __shared__ __align__(16) f16 sAh[128][40];
  __shared__ __align__(16) f16 sAl[128][40];
  __shared__ __align__(16) f16 sB[128][40];
  __shared__ float sT[128][4];

  int nb = blockIdx.x;
  int m0 = blockIdx.y * 128;
  bool is_v = nb >= 8;
  int n0 = (nb & 7) * 128;
  int mat = is_v ? 2 : 1;
  const f16* Wm = Wh + (size_t)mat * 1048576;
  const float* ttv = is_v ? tv : tk;
  const float* LBm = is_v ? LBv : LBk;
  const float* qb = qbias + mat * 1024;
  KVT* outp = is_v ? vout : kout;

  int tid = threadIdx.x;
  int lane = tid & 63, wave = tid >> 6;
  int wm = (wave >> 1) * 64, wn = (wave & 1) * 64;
  int row = lane & 15, kq = lane >> 4;

  f32x4 acc[4][4];
  #pragma unroll
  for (int i = 0; i < 4; ++i)
    #pragma unroll
    for (int j = 0; j < 4; ++j) acc[i][j] = (f32x4){0.f, 0.f, 0.f, 0.f};

  int sr = tid >> 1, seg = tid & 1;
  const float* asrc = zp + (size_t)(m0 + sr) * 1024 + seg * 16;
  const f16* bsrc = Wm + (size_t)(n0 + sr) * 1024 + seg * 16;

  for (int k0 = 0; k0 < 1024; k0 += 32) {
    __syncthreads();
    float xs[16];
    const float4* a4 = (const float4*)(asrc + k0);
    *(float4*)&xs[0] = a4[0];
    *(float4*)&xs[4] = a4[1];
    *(float4*)&xs[8] = a4[2];
    *(float4*)&xs[12] = a4[3];
    f16 hs[16], ls[16];
    #pragma unroll
    for (int i = 0; i < 16; ++i) {
      f16 h = (f16)xs[i];
      hs[i] = h;
      ls[i] = (f16)(xs[i] - (float)h);
    }
    *(f16x8*)&sAh[sr][seg * 16] = *(f16x8*)&hs[0];
    *(f16x8*)&sAh[sr][seg * 16 + 8] = *(f16x8*)&hs[8];
    *(f16x8*)&sAl[sr][seg * 16] = *(f16x8*)&ls[0];
    *(f16x8*)&sAl[sr][seg * 16 + 8] = *(f16x8*)&ls[8];
    const f16x8* b8 = (const f16x8*)(bsrc + k0);
    *(f16x8*)&sB[sr][seg * 16] = b8[0];
    *(f16x8*)&sB[sr][seg * 16 + 8] = b8[1];
    __syncthreads();
    f16x8 ah[4], al[4], bf[4];
    #pragma unroll
    for (int mi = 0; mi < 4; ++mi) {
      ah[mi] = *(const f16x8*)&sAh[wm + mi * 16 + row][kq * 8];
      al[mi] = *(const f16x8*)&sAl[wm + mi * 16 + row][kq * 8];
    }
    #pragma unroll
    for (int ni = 0; ni < 4; ++ni) bf[ni] = *(const f16x8*)&sB[wn + ni * 16 + row][kq * 8];
    #pragma unroll
    for (int mi = 0; mi < 4; ++mi)
      #pragma unroll
      for (int ni = 0; ni < 4; ++ni)
        acc[mi][ni] = __builtin_amdgcn_mfma_f32_16x16x32_f16(ah[mi], bf[ni], acc[mi][ni], 0, 0, 0);
    #pragma unroll
    for (int mi = 0; mi < 4; ++mi)
      #pragma unroll
      for (int ni = 0; ni < 4; ++ni)
        acc[mi][ni] = __builtin_amdgcn_mfma_f32_16x16x32_f16(al[mi], bf[ni], acc[mi][ni], 0, 0, 0);
  }
  ((float2*)sT)[tid] = ((const float2*)(ttv + (size_t)m0 * 4))[tid];
  __syncthreads();
  float scale = __uint_as_float(absmax[mat]) * (1.0f / 7.0f);
  #pragma unroll
  for (int ni = 0; ni < 4; ++ni) {
    int ncol = n0 + wn + ni * 16 + row;
    int h = ncol >> 7, d = ncol & 127;
    float4 lb = *(const float4*)(LBm + ncol * 4);
    float bias = qb[ncol];
    #pragma unroll
    for (int mi = 0; mi < 4; ++mi) {
      #pragma unroll
      for (int j = 0; j < 4; ++j) {
        int mloc = wm + mi * 16 + kq * 4 + j;
        int m = m0 + mloc;
        int p = m >> 4, b = m & 15;
        float4 t4 = *(const float4*)&sT[mloc][0];
        float val = scale * acc[mi][ni][j] + bias +
                    4.0f * (t4.x * lb.x + t4.y * lb.y + t4.z * lb.z + t4.w * lb.w);
        outp[(((size_t)(b * 8 + h)) * 2048 + p) * 128 + d] = (KVT)val;
      }
    }
  }
}

// ---------------- fast fused K+V GEMM (global_load_lds, f16 hi/lo inputs) ----
// XCD-aware swizzle: all 16 nb-blocks of one m0-group land on the same XCD
// consecutively -> A panel fetched from HBM once per group, L2-hit after.
// Epilogue: LDS-transposed so every HBM write is a full 512B row (dwordx4).
template <typename KVT>
__global__ void __launch_bounds__(256, 3) kv_gemm_fast_kernel(
    const f16* __restrict__ zph, const f16* __restrict__ zpl,
    const f16* __restrict__ Wh, const unsigned* __restrict__ absmax,
    const float* __restrict__ qbias, const float* __restrict__ tk,
    const float* __restrict__ tv, const float* __restrict__ LBk,
    const float* __restrict__ LBv, KVT* __restrict__ kout, KVT* __restrict__ vout) {
  __shared__ __align__(16) f16 sbuf[24576];  // 48 KB: sAh | sAl | sB, reused as tbuf
  __shared__ float sT[128][4];
  f16* sAh = sbuf;
  f16* sAl = sbuf + 8192;
  f16* sB = sbuf + 16384;
  float* tbuf = (float*)sbuf;  // 64 x 132 f32 = 33792 B (epilogue only)

  // bijective XCD swizzle: linear = bx + 16*by; xcd = linear%8 stays fixed for
  // all 16 nb of one group g.
  int linear = blockIdx.x + (blockIdx.y << 4);
  int xcd = linear & 7;
  int slot = linear >> 3;          // 0..511
  int nb = slot & 15;              // 16 nb values consecutive per XCD queue
  int g = ((slot >> 4) << 3) + xcd;  // 0..255
  int m0 = g << 7;

  bool is_v = nb >= 8;
  int n0 = (nb & 7) * 128;
  int mat = is_v ? 2 : 1;
  int h = nb & 7;  // head index of this 128-col band
  const f16* Wm = Wh + (size_t)mat * 1048576;
  const float* ttv = is_v ? tv : tk;
  const float* LBm = is_v ? LBv : LBk;
  const float* qb = qbias + mat * 1024;
  KVT* outp = is_v ? vout : kout;

  int tid = threadIdx.x;
  int lane = tid & 63, wave = tid >> 6;
  int wm = (wave >> 1) * 64, wn = (wave & 1) * 64;
  int row = lane & 15, kq = lane >> 4;

  const f16* srcAh = zph + (size_t)m0 * 1024;
  const f16* srcAl = zpl + (size_t)m0 * 1024;
  const f16* srcB = Wm + (size_t)n0 * 1024;

  int goff[4], lbase[4];
  #pragma unroll
  for (int r = 0; r < 4; ++r) {
    int L = r * 256 + tid;
    int rw = L >> 3, cc = L & 7, cs = cc ^ (rw & 7);
    goff[r] = rw * 1024 + cs * 8;
    lbase[r] = (r * 256 + (wave << 6)) * 8;
  }

  f32x4 acc[4][4];
  #pragma unroll
  for (int i = 0; i < 4; ++i)
    #pragma unroll
    for (int j = 0; j < 4; ++j) acc[i][j] = (f32x4){0.f, 0.f, 0.f, 0.f};

  for (int k0 = 0; k0 < 1024; k0 += 64) {
    __syncthreads();
    #pragma unroll
    for (int r = 0; r < 4; ++r) {
      gload16(srcAh + goff[r] + k0, sAh + lbase[r]);
      gload16(srcAl + goff[r] + k0, sAl + lbase[r]);
      gload16(srcB + goff[r] + k0, sB + lbase[r]);
    }
    __syncthreads();
    #pragma unroll
    for (int ks = 0; ks < 2; ++ks) {
      int ch = (ks * 4 + kq) ^ (row & 7);
      f16x8 ah[4], al[4], bf[4];
      #pragma unroll
      for (int mi = 0; mi < 4; ++mi) {
        int ad = (wm + mi * 16 + row) * 64 + ch * 8;
        ah[mi] = *(const f16x8*)&sAh[ad];
        al[mi] = *(const f16x8*)&sAl[ad];
      }
      #pragma unroll
      for (int ni = 0; ni < 4; ++ni)
        bf[ni] = *(const f16x8*)&sB[(wn + ni * 16 + row) * 64 + ch * 8];
      #pragma unroll
      for (int mi = 0; mi < 4; ++mi)
        #pragma unroll
        for (int ni = 0; ni < 4; ++ni)
          acc[mi][ni] = __builtin_amdgcn_mfma_f32_16x16x32_f16(ah[mi], bf[ni], acc[mi][ni], 0, 0, 0);
      #pragma unroll
      for (int mi = 0; mi < 4; ++mi)
        #pragma unroll
        for (int ni = 0; ni < 4; ++ni)
          acc[mi][ni] = __builtin_amdgcn_mfma_f32_16x16x32_f16(al[mi], bf[ni], acc[mi][ni], 0, 0, 0);
    }
  }
  ((float2*)sT)[tid] = ((const float2*)(ttv + (size_t)m0 * 4))[tid];
  __syncthreads();
  float scale = __uint_as_float(absmax[mat]) * (1.0f / 7.0f);
  // hoist per-column epilogue constants (fixed per thread)
  float biasv[4];
  float4 lbv[4];
  #pragma unroll
  for (int ni = 0; ni < 4; ++ni) {
    int ncol = n0 + wn + ni * 16 + row;
    biasv[ni] = qb[ncol];
    lbv[ni] = *(const float4*)(LBm + ncol * 4);
  }
  int lh = lane >> 5, l5 = lane & 31;
  #pragma unroll
  for (int halfsel = 0; halfsel < 2; ++halfsel) {
    __syncthreads();
    if ((wave >> 1) == halfsel) {
      #pragma unroll
      for (int ni = 0; ni < 4; ++ni) {
        #pragma unroll
        for (int mi = 0; mi < 4; ++mi) {
          #pragma unroll
          for (int j = 0; j < 4; ++j) {
            int ml = mi * 16 + kq * 4 + j;  // local row within this 64-half
            float4 t4 = *(const float4*)&sT[wm + ml][0];
            tbuf[ml * 132 + wn + ni * 16 + row] =
                scale * acc[mi][ni][j] + biasv[ni] +
                4.0f * (t4.x * lbv[ni].x + t4.y * lbv[ni].y + t4.z * lbv[ni].z +
                        t4.w * lbv[ni].w);
          }
        }
      }
    }
    __syncthreads();
    #pragma unroll
    for (int it = 0; it < 8; ++it) {
      int ml = it * 8 + wave * 2 + lh;
      int m = m0 + halfsel * 64 + ml;
      int p = m >> 4, b = m & 15;
      float4 v = *(const float4*)&tbuf[ml * 132 + l5 * 4];
      KVT* dst = outp + (((size_t)(b * 8 + h)) * 2048 + p) * 128 + l5 * 4;
      if constexpr (sizeof(KVT) == 4) {
        *(float4*)dst = v;
      } else {
        f16x4 hv = {(f16)v.x, (f16)v.y, (f16)v.z, (f16)v.w};
        *(f16x4*)dst = hv;
      }
    }
  }
}

// ---------------- attention (split-P flash over [BH][P][128] KV) ----------
template <typename KVT>
__device__ __forceinline__ float4 ld4(const KVT* p) {
  if constexpr (sizeof(KVT) == 4) {
    return *reinterpret_cast<const float4*>(p);
  } else {
    f16x4 v = *reinterpret_cast<const f16x4*>(p);
    return make_float4((float)v[0], (float)v[1], (float)v[2], (float)v[3]);
  }
}

template <typename KVT>
__global__ void __launch_bounds__(256) attn_part_kernel(
    const float* __restrict__ qbuf, const KVT* __restrict__ kbuf,
    const KVT* __restrict__ vbuf, const float* __restrict__ rel_bias,
    const int* __restrict__ curr_pos_p, float* __restrict__ m_part,
    float* __restrict__ l_part, float* __restrict__ o_part) {
  __shared__ float sS[256];
  __shared__ float red[8];
  __shared__ float sOv[8][132];
  int bh = blockIdx.x;            // b*8+h
  int c = blockIdx.y;             // P chunk
  int b = bh >> 3, h = bh & 7;
  int p0 = c * 256;
  int tid = threadIdx.x, lane = tid & 63, wave = tid >> 6;
  int j4 = lane & 31, ph = lane >> 5;
  float4 qv = *(const float4*)(qbuf + b * 1024 + h * 128 + j4 * 4);
  int off = *curr_pos_p - NP + 64;
  const KVT* kb = kbuf + ((size_t)bh * 2048 + p0) * 128;
  for (int i = 0; i < 32; ++i) {
    int pl = i * 8 + wave * 2 + ph;
    float4 kv = ld4(kb + (size_t)pl * 128 + j4 * 4);
    int idx = min(max(p0 + pl + off, 0), 128);
    float4 rb = *(const float4*)(rel_bias + idx * 1024 + h * 128 + j4 * 4);
    float a = qv.x * (kv.x + rb.x) + qv.y * (kv.y + rb.y) +
              qv.z * (kv.z + rb.z) + qv.w * (kv.w + rb.w);
    a += __shfl_xor(a, 16);
    a += __shfl_xor(a, 8);
    a += __shfl_xor(a, 4);
    a += __shfl_xor(a, 2);
    a += __shfl_xor(a, 1);
    if (j4 == 0) sS[pl] = a * 0.125f;  // 1/sqrt(64)
  }
  __syncthreads();
  float v = sS[tid];
  float mx = v;
  #pragma unroll
  for (int k = 32; k >= 1; k >>= 1) mx = fmaxf(mx, __shfl_xor(mx, k));
  if (lane == 0) red[wave] = mx;
  __syncthreads();
  mx = fmaxf(fmaxf(red[0], red[1]), fmaxf(red[2], red[3]));
  float e = expf(v - mx);
  sS[tid] = e;
  float sum = e;
  #pragma unroll
  for (int k = 32; k >= 1; k >>= 1) sum += __shfl_xor(sum, k);
  if (lane == 0) red[4 + wave] = sum;
  __syncthreads();
  float l = red[4] + red[5] + red[6] + red[7];
  // PV: 8 p-groups x 32 d4-lanes, float4 per lane
  int d4 = tid & 31, pg = tid >> 5;
  const KVT* vb = vbuf + ((size_t)bh * 2048 + p0 + pg * 32) * 128;
  float4 a4 = make_float4(0.f, 0.f, 0.f, 0.f);
  #pragma unroll 4
  for (int i = 0; i < 32; ++i) {
    float s = sS[pg * 32 + i];
    float4 vv = ld4(vb + (size_t)i * 128 + d4 * 4);
    a4.x += s * vv.x;
    a4.y += s * vv.y;
    a4.z += s * vv.z;
    a4.w += s * vv.w;
  }
  *(float4*)&sOv[pg][d4 * 4] = a4;
  __syncthreads();
  if (tid < 128) {
    float o = 0.f;
    #pragma unroll
    for (int gI = 0; gI < 8; ++gI) o += sOv[gI][tid];
    int pc = bh * 8 + c;
    o_part[pc * 128 + tid] = o;
    if (tid == 0) {
      m_part[pc] = mx;
      l_part[pc] = l;
    }
  }
}

__global__ void __launch_bounds__(128) attn_combine_kernel(
    const float* __restrict__ m_part, const float* __restrict__ l_part,
    const float* __restrict__ o_part, float* __restrict__ attout) {
  int bh = blockIdx.x;
  int d = threadIdx.x;
  float M = -1e30f;
  #pragma unroll
  for (int c = 0; c < 8; ++c) M = fmaxf(M, m_part[bh * 8 + c]);
  float L = 0.f, o = 0.f;
  #pragma unroll
  for (int c = 0; c < 8; ++c) {
    float w = expf(m_part[bh * 8 + c] - M);
    L += w * l_part[bh * 8 + c];
    o += w * o_part[(bh * 8 + c) * 128 + d];
  }
  int b = bh >> 3, h = bh & 7;
  attout[b * 1024 + h * 128 + d] = o / L;
}

// ---------------- host launch ----------------
extern "C" void kernel_launch(void* const* d_in, const int* in_sizes, int n_in,
                              void* d_out, int out_size, void* d_ws, size_t ws_size,
                              hipStream_t stream) {
  const int* curr_pos = (const int*)d_in[0];
  const float* z_curr = (const float*)d_in[1];
  const float* z_past = (const float*)d_in[2];
  const float* rel_bias = (const float*)d_in[3];
  const float* Wq = (const float*)d_in[4];
  const float* bq = (const float*)d_in[5];
  const float* Aq = (const float*)d_in[6];
  const float* LBq = (const float*)d_in[7];
  const float* Wk = (const float*)d_in[8];
  const float* bk = (const float*)d_in[9];
  const float* Ak = (const float*)d_in[10];
  const float* LBk = (const float*)d_in[11];
  const float* Wv = (const float*)d_in[12];
  const float* bv = (const float*)d_in[13];
  const float* Av = (const float*)d_in[14];
  const float* LBv = (const float*)d_in[15];
  const float* Wo = (const float*)d_in[16];
  const float* bo = (const float*)d_in[17];
  const float* Ao = (const float*)d_in[18];
  const float* LBo = (const float*)d_in[19];

  char* ws = (char*)d_ws;
  unsigned* absmax = (unsigned*)(ws + OFF_ABSMAX);
  float* t_q = (float*)(ws + OFF_TQ);
  float* t_o = (float*)(ws + OFF_TO);
  float* qbias = (float*)(ws + OFF_QBIAS);
  f16* xqh = (f16*)(ws + OFF_XQH);
  f16* xql = (f16*)(ws + OFF_XQL);
  f16* xoh = (f16*)(ws + OFF_XOH);
  f16* xol = (f16*)(ws + OFF_XOL);
  float* qbuf = (float*)(ws + OFF_QBUF);
  float* attout = (float*)(ws + OFF_ATT);
  float* pm = (float*)(ws + OFF_PM);
  float* pl = (float*)(ws + OFF_PL);
  float* po = (float*)(ws + OFF_PO);
  f16* Wh = (f16*)(ws + OFF_WH);
  float* t_k = (float*)(ws + OFF_TK);
  float* t_v = (float*)(ws + OFF_TV);
  char* kvbase = ws + OFF_KV;

  bool f32kv = ws_size >= (size_t)OFF_KV + 2ull * 134217728ull;
  size_t kvBytes1 = f32kv ? 134217728ull : 67108864ull;
  f16* zph = (f16*)(kvbase + 2 * kvBytes1);
  f16* zpl = (f16*)(kvbase + 2 * kvBytes1 + 67108864ull);
  bool fast = ws_size >= (size_t)OFF_KV + 2 * kvBytes1 + 2ull * 67108864ull;

  hipMemsetAsync(absmax, 0, 16, stream);
  absmax_kernel<<<256, 256, 0, stream>>>(Wq, Wk, Wv, Wo, absmax);
  bias_quant_kernel<<<4, 256, 0, stream>>>(bq, bk, bv, bo, qbias);
  quantW_kernel<<<4096, 256, 0, stream>>>(Wq, Wk, Wv, Wo, absmax, Wh);
  cvt_hilo_kernel<<<16, 256, 0, stream>>>(z_curr, xqh, xql);
  lora_t_small_kernel<<<1, 256, 0, stream>>>(z_curr, Aq, t_q);
  gemv_mfma_kernel<<<16, 256, 0, stream>>>(xqh, xql, Wh, absmax, 0, qbias, t_q, LBq, qbuf);
  lora_t_big_kernel<<<2048, 256, 0, stream>>>(z_past, Ak, Av, t_k, t_v,
                                              fast ? zph : nullptr, fast ? zpl : nullptr);
  if (f32kv) {
    float* kb = (float*)kvbase;
    float* vb = (float*)(kvbase + kvBytes1);
    if (fast)
      kv_gemm_fast_kernel<float><<<dim3(16, 256), 256, 0, stream>>>(
          zph, zpl, Wh, absmax, qbias, t_k, t_v, LBk, LBv, kb, vb);
    else
      kv_gemm_kernel<float><<<dim3(16, 256), 256, 0, stream>>>(
          z_past, Wh, absmax, qbias, t_k, t_v, LBk, LBv, kb, vb);
    attn_part_kernel<float><<<dim3(128, 8), 256, 0, stream>>>(
        qbuf, kb, vb, rel_bias, curr_pos, pm, pl, po);
  } else {
    f16* kb = (f16*)kvbase;
    f16* vb = (f16*)(kvbase + kvBytes1);
    if (fast)
      kv_gemm_fast_kernel<f16><<<dim3(16, 256), 256, 0, stream>>>(
          zph, zpl, Wh, absmax, qbias, t_k, t_v, LBk, LBv, kb, vb);
    else
      kv_gemm_kernel<f16><<<dim3(16, 256), 256, 0, stream>>>(
          z_past, Wh, absmax, qbias, t_k, t_v, LBk, LBv, kb, vb);
    attn_part_kernel<f16><<<dim3(128, 8), 256, 0, stream>>>(
        qbuf, kb, vb, rel_bias, curr_pos, pm, pl, po);
  }
  attn_combine_kernel<<<128, 128, 0, stream>>>(pm, pl, po, attout);
  cvt_hilo_kernel<<<16, 256, 0, stream>>>(attout, xoh, xol);
  lora_t_small_kernel<<<1, 256, 0, stream>>>(attout, Ao, t_o);
  gemv_mfma_kernel<<<16, 256, 0, stream>>>(xoh, xol, Wh + 3ull * 1048576ull, absmax, 3,
                                           qbias + 3 * 1024, t_o, LBo, (float*)d_out);
}

// Round 4
// 823.289 us; speedup vs baseline: 1.2205x; 1.0047x over previous
//
#include <hip/hip_runtime.h>
#include <math.h>

typedef _Float16 f16;
typedef _Float16 f16x8 __attribute__((ext_vector_type(8)));
typedef _Float16 f16x4 __attribute__((ext_vector_type(4)));
typedef float f32x4 __attribute__((ext_vector_type(4)));

#define NP 2048
#define M_ROWS 32768

// ---------------- ws layout (bytes) ----------------
#define OFF_ABSMAX 0u
#define OFF_TQ     256u
#define OFF_TO     512u
#define OFF_QBIAS  1024u        // 4*1024 f32
#define OFF_XQH    32768u       // 16*1024 f16
#define OFF_XQL    65536u
#define OFF_XOH    98304u
#define OFF_XOL    131072u
#define OFF_QBUF   163840u      // 16*1024 f32
#define OFF_ATT    229376u      // 16*1024 f32 (ends 294912)
#define OFF_PM     294912u      // 1024 f32 attn partial max
#define OFF_PL     299008u      // 1024 f32 attn partial sum
#define OFF_PO     303104u      // 1024*128 f32 attn partial out (ends 827392)
#define OFF_WH     1048576u     // 4 * 1M f16 = 8 MB
#define OFF_TK     9437184u     // 32768*4 f32
#define OFF_TV     9961472u
#define OFF_KV     10485760u    // K,V f16 (64MB each); then zph/zpl f16 hi/lo

__device__ __forceinline__ float qint_of(float w, float scale) {
    return fminf(7.f, fmaxf(-8.f, rintf(w / (scale + 1e-8f))));
}

__device__ __forceinline__ void gload16(const void* g, void* l) {
  __builtin_amdgcn_global_load_lds((const __attribute__((address_space(1))) void*)g,
                                   (__attribute__((address_space(3))) void*)l, 16, 0, 0);
}

// ---------------- absmax over 4 weight matrices ----------------
__global__ void __launch_bounds__(256) absmax_kernel(
    const float* __restrict__ W0, const float* __restrict__ W1,
    const float* __restrict__ W2, const float* __restrict__ W3,
    unsigned* __restrict__ absmax) {
  int mat = blockIdx.x >> 6;
  int blk = blockIdx.x & 63;
  const float* W = mat == 0 ? W0 : mat == 1 ? W1 : mat == 2 ? W2 : W3;
  int tid = blk * 256 + threadIdx.x;      // 0..16383
  const float4* W4 = (const float4*)W;
  float m = 0.f;
  #pragma unroll
  for (int i = 0; i < 16; ++i) {
    float4 v = W4[tid + i * 16384];
    m = fmaxf(m, fmaxf(fmaxf(fabsf(v.x), fabsf(v.y)), fmaxf(fabsf(v.z), fabsf(v.w))));
  }
  #pragma unroll
  for (int k = 32; k >= 1; k >>= 1) m = fmaxf(m, __shfl_xor(m, k));
  __shared__ float sm[4];
  if ((threadIdx.x & 63) == 0) sm[threadIdx.x >> 6] = m;
  __syncthreads();
  if (threadIdx.x == 0) {
    m = fmaxf(fmaxf(sm[0], sm[1]), fmaxf(sm[2], sm[3]));
    atomicMax(&absmax[mat], __float_as_uint(m));
  }
}

// ---------------- quantize biases (simq) ----------------
__global__ void __launch_bounds__(256) bias_quant_kernel(
    const float* __restrict__ b0, const float* __restrict__ b1,
    const float* __restrict__ b2, const float* __restrict__ b3,
    float* __restrict__ qbias) {
  int mat = blockIdx.x;
  const float* bb = mat == 0 ? b0 : mat == 1 ? b1 : mat == 2 ? b2 : b3;
  int t = threadIdx.x;
  float4 v = ((const float4*)bb)[t];
  float m = fmaxf(fmaxf(fabsf(v.x), fabsf(v.y)), fmaxf(fabsf(v.z), fabsf(v.w)));
  #pragma unroll
  for (int k = 32; k >= 1; k >>= 1) m = fmaxf(m, __shfl_xor(m, k));
  __shared__ float sm[4];
  if ((t & 63) == 0) sm[t >> 6] = m;
  __syncthreads();
  float M = fmaxf(fmaxf(sm[0], sm[1]), fmaxf(sm[2], sm[3]));
  float scale = M * (1.0f / 7.0f);
  float4 q;
  q.x = (M == 0.f) ? v.x : qint_of(v.x, scale) * scale;
  q.y = (M == 0.f) ? v.y : qint_of(v.y, scale) * scale;
  q.z = (M == 0.f) ? v.z : qint_of(v.z, scale) * scale;
  q.w = (M == 0.f) ? v.w : qint_of(v.w, scale) * scale;
  ((float4*)(qbias + mat * 1024))[t] = q;
}

// ---------------- quantize W -> f16 integer values ----------------
__global__ void __launch_bounds__(256) quantW_kernel(
    const float* __restrict__ W0, const float* __restrict__ W1,
    const float* __restrict__ W2, const float* __restrict__ W3,
    const unsigned* __restrict__ absmax, f16* __restrict__ Wh) {
  int gid = blockIdx.x * 256 + threadIdx.x;  // float4 units
  int mat = gid >> 18;
  int idx = gid & 262143;
  const float* W = mat == 0 ? W0 : mat == 1 ? W1 : mat == 2 ? W2 : W3;
  float scale = __uint_as_float(absmax[mat]) * (1.0f / 7.0f);
  float4 v = ((const float4*)W)[idx];
  f16x4 r;
  r[0] = (f16)qint_of(v.x, scale);
  r[1] = (f16)qint_of(v.y, scale);
  r[2] = (f16)qint_of(v.z, scale);
  r[3] = (f16)qint_of(v.w, scale);
  *(f16x4*)(Wh + (size_t)mat * 1048576 + (size_t)idx * 4) = r;
}

// ---------------- f32 -> f16 hi/lo split (16K elems) ----------------
__global__ void __launch_bounds__(256) cvt_hilo_kernel(
    const float* __restrict__ x, f16* __restrict__ hi, f16* __restrict__ lo) {
  int i = blockIdx.x * 256 + threadIdx.x;
  float4 v = ((const float4*)x)[i];
  f16 h0 = (f16)v.x, h1 = (f16)v.y, h2 = (f16)v.z, h3 = (f16)v.w;
  f16x4 hv = {h0, h1, h2, h3};
  f16x4 lv = {(f16)(v.x - (float)h0), (f16)(v.y - (float)h1),
              (f16)(v.z - (float)h2), (f16)(v.w - (float)h3)};
  *(f16x4*)(hi + (size_t)i * 4) = hv;
  *(f16x4*)(lo + (size_t)i * 4) = lv;
}

// ---------------- lora t for 16-row x: t[16][4] ----------------
__global__ void __launch_bounds__(256) lora_t_small_kernel(
    const float* __restrict__ x, const float* __restrict__ A, float* __restrict__ t) {
  int tt = threadIdx.x;
  int b = tt >> 4;
  int r = (tt >> 2) & 3;
  int s = tt & 3;
  const float4* xv = (const float4*)(x + b * 1024 + s * 256);
  const float4* av = (const float4*)(A + r * 1024 + s * 256);
  float acc = 0.f;
  #pragma unroll 4
  for (int i = 0; i < 64; ++i) {
    float4 a = xv[i], c = av[i];
    acc += a.x * c.x + a.y * c.y + a.z * c.z + a.w * c.w;
  }
  acc += __shfl_xor(acc, 1);
  acc += __shfl_xor(acc, 2);
  if (s == 0) t[b * 4 + r] = acc;
}

// ---------------- lora t for z_past + optional f16 hi/lo split ----------------
__global__ void __launch_bounds__(256) lora_t_big_kernel(
    const float* __restrict__ zp, const float* __restrict__ Ak,
    const float* __restrict__ Av, float* __restrict__ tk, float* __restrict__ tv,
    f16* __restrict__ zph, f16* __restrict__ zpl) {
  __shared__ float sA[8 * 1024];
  for (int i = 0; i < 8; ++i) {
    int f4 = threadIdx.x + i * 256;
    float4 v = (f4 < 1024) ? ((const float4*)Ak)[f4] : ((const float4*)Av)[f4 - 1024];
    ((float4*)sA)[f4] = v;
  }
  __syncthreads();
  int lane = threadIdx.x & 63, wave = threadIdx.x >> 6;
  for (int it = 0; it < 4; ++it) {
    int m = blockIdx.x * 16 + wave * 4 + it;
    const float4* xr = (const float4*)(zp + (size_t)m * 1024);
    float acc[8] = {0.f, 0.f, 0.f, 0.f, 0.f, 0.f, 0.f, 0.f};
    for (int c = lane; c < 256; c += 64) {
      float4 xv = xr[c];
      if (zph) {
        f16 h0 = (f16)xv.x, h1 = (f16)xv.y, h2 = (f16)xv.z, h3 = (f16)xv.w;
        f16x4 hv = {h0, h1, h2, h3};
        f16x4 lv = {(f16)(xv.x - (float)h0), (f16)(xv.y - (float)h1),
                    (f16)(xv.z - (float)h2), (f16)(xv.w - (float)h3)};
        *(f16x4*)(zph + (size_t)m * 1024 + c * 4) = hv;
        *(f16x4*)(zpl + (size_t)m * 1024 + c * 4) = lv;
      }
      #pragma unroll
      for (int r = 0; r < 8; ++r) {
        float4 a = ((const float4*)sA)[r * 256 + c];
        acc[r] += xv.x * a.x + xv.y * a.y + xv.z * a.z + xv.w * a.w;
      }
    }
    #pragma unroll
    for (int k = 32; k >= 1; k >>= 1) {
      #pragma unroll
      for (int r = 0; r < 8; ++r) acc[r] += __shfl_xor(acc[r], k);
    }
    if (lane == 0) {
      tk[m * 4 + 0] = acc[0]; tk[m * 4 + 1] = acc[1];
      tk[m * 4 + 2] = acc[2]; tk[m * 4 + 3] = acc[3];
      tv[m * 4 + 0] = acc[4]; tv[m * 4 + 1] = acc[5];
      tv[m * 4 + 2] = acc[6]; tv[m * 4 + 3] = acc[7];
    }
  }
}

// ---------------- MFMA GEMV (M=16) ----------------
__global__ void __launch_bounds__(256) gemv_mfma_kernel(
    const f16* __restrict__ xhi, const f16* __restrict__ xlo,
    const f16* __restrict__ Wm, const unsigned* __restrict__ absmax, int mat,
    const float* __restrict__ qb, const float* __restrict__ t,
    const float* __restrict__ LB, float* __restrict__ out) {
  int wave = threadIdx.x >> 6, lane = threadIdx.x & 63;
  int nf = blockIdx.x * 4 + wave;
  int n0 = nf * 16;
  int row = lane & 15, kq = lane >> 4;
  f32x4 acc = {0.f, 0.f, 0.f, 0.f};
  const f16* xh = xhi + row * 1024 + kq * 8;
  const f16* xl = xlo + row * 1024 + kq * 8;
  const f16* wp = Wm + (size_t)(n0 + row) * 1024 + kq * 8;
  #pragma unroll 4
  for (int k0 = 0; k0 < 1024; k0 += 32) {
    f16x8 ah = *(const f16x8*)(xh + k0);
    f16x8 al = *(const f16x8*)(xl + k0);
    f16x8 bb = *(const f16x8*)(wp + k0);
    acc = __builtin_amdgcn_mfma_f32_16x16x32_f16(ah, bb, acc, 0, 0, 0);
    acc = __builtin_amdgcn_mfma_f32_16x16x32_f16(al, bb, acc, 0, 0, 0);
  }
  float scale = __uint_as_float(absmax[mat]) * (1.0f / 7.0f);
  int col = n0 + row;
  float bias = qb[col];
  float4 lb = *(const float4*)(LB + col * 4);
  #pragma unroll
  for (int j = 0; j < 4; ++j) {
    int m = kq * 4 + j;
    float4 tvv = *(const float4*)(t + m * 4);
    out[m * 1024 + col] =
        scale * acc[j] + bias + 4.0f * (tvv.x * lb.x + tvv.y * lb.y + tvv.z * lb.z + tvv.w * lb.w);
  }
}

// ---------------- legacy fused K+V GEMM (reg-staged; fallback) ----
__global__ void __launch_bounds__(256, 2) kv_gemm_kernel(
    const float* __restrict__ zp, const f16* __restrict__ Wh,
    const unsigned* __restrict__ absmax, const float* __restrict__ qbias,
    const float* __restrict__ tk, const float* __restrict__ tv,
    const float* __restrict__ LBk, const float* __restrict__ LBv,
    f16* __restrict__ kout, f16* __restrict__ vout) {
  __shared__ __align__(16) f16 sAh[128][40];
  __shared__ __align__(16) f16 sAl[128][40];
  __shared__ __align__(16) f16 sB[128][40];
  __shared__ float sT[128][4];

  int nb = blockIdx.x;
  int m0 = blockIdx.y * 128;
  bool is_v = nb >= 8;
  int n0 = (nb & 7) * 128;
  int mat = is_v ? 2 : 1;
  const f16* Wm = Wh + (size_t)mat * 1048576;
  const float* ttv = is_v ? tv : tk;
  const float* LBm = is_v ? LBv : LBk;
  const float* qb = qbias + mat * 1024;
  f16* outp = is_v ? vout : kout;

  int tid = threadIdx.x;
  int lane = tid & 63, wave = tid >> 6;
  int wm = (wave >> 1) * 64, wn = (wave & 1) * 64;
  int row = lane & 15, kq = lane >> 4;

  f32x4 acc[4][4];
  #pragma unroll
  for (int i = 0; i < 4; ++i)
    #pragma unroll
    for (int j = 0; j < 4; ++j) acc[i][j] = (f32x4){0.f, 0.f, 0.f, 0.f};

  int sr = tid >> 1, seg = tid & 1;
  const float* asrc = zp + (size_t)(m0 + sr) * 1024 + seg * 16;
  const f16* bsrc = Wm + (size_t)(n0 + sr) * 1024 + seg * 16;

  for (int k0 = 0; k0 < 1024; k0 += 32) {
    __syncthreads();
    float xs[16];
    const float4* a4 = (const float4*)(asrc + k0);
    *(float4*)&xs[0] = a4[0];
    *(float4*)&xs[4] = a4[1];
    *(float4*)&xs[8] = a4[2];
    *(float4*)&xs[12] = a4[3];
    f16 hs[16], ls[16];
    #pragma unroll
    for (int i = 0; i < 16; ++i) {
      f16 h = (f16)xs[i];
      hs[i] = h;
      ls[i] = (f16)(xs[i] - (float)h);
    }
    *(f16x8*)&sAh[sr][seg * 16] = *(f16x8*)&hs[0];
    *(f16x8*)&sAh[sr][seg * 16 + 8] = *(f16x8*)&hs[8];
    *(f16x8*)&sAl[sr][seg * 16] = *(f16x8*)&ls[0];
    *(f16x8*)&sAl[sr][seg * 16 + 8] = *(f16x8*)&ls[8];
    const f16x8* b8 = (const f16x8*)(bsrc + k0);
    *(f16x8*)&sB[sr][seg * 16] = b8[0];
    *(f16x8*)&sB[sr][seg * 16 + 8] = b8[1];
    __syncthreads();
    f16x8 ah[4], al[4], bf[4];
    #pragma unroll
    for (int mi = 0; mi < 4; ++mi) {
      ah[mi] = *(const f16x8*)&sAh[wm + mi * 16 + row][kq * 8];
      al[mi] = *(const f16x8*)&sAl[wm + mi * 16 + row][kq * 8];
    }
    #pragma unroll
    for (int ni = 0; ni < 4; ++ni) bf[ni] = *(const f16x8*)&sB[wn + ni * 16 + row][kq * 8];
    #pragma unroll
    for (int mi = 0; mi < 4; ++mi)
      #pragma unroll
      for (int ni = 0; ni < 4; ++ni)
        acc[mi][ni] = __builtin_amdgcn_mfma_f32_16x16x32_f16(ah[mi], bf[ni], acc[mi][ni], 0, 0, 0);
    #pragma unroll
    for (int mi = 0; mi < 4; ++mi)
      #pragma unroll
      for (int ni = 0; ni < 4; ++ni)
        acc[mi][ni] = __builtin_amdgcn_mfma_f32_16x16x32_f16(al[mi], bf[ni], acc[mi][ni], 0, 0, 0);
  }
  ((float2*)sT)[tid] = ((const float2*)(ttv + (size_t)m0 * 4))[tid];
  __syncthreads();
  float scale = __uint_as_float(absmax[mat]) * (1.0f / 7.0f);
  #pragma unroll
  for (int ni = 0; ni < 4; ++ni) {
    int ncol = n0 + wn + ni * 16 + row;
    int h = ncol >> 7, d = ncol & 127;
    float4 lb = *(const float4*)(LBm + ncol * 4);
    float bias = qb[ncol];
    #pragma unroll
    for (int mi = 0; mi < 4; ++mi) {
      #pragma unroll
      for (int j = 0; j < 4; ++j) {
        int mloc = wm + mi * 16 + kq * 4 + j;
        int m = m0 + mloc;
        int p = m >> 4, b = m & 15;
        float4 t4 = *(const float4*)&sT[mloc][0];
        float val = scale * acc[mi][ni][j] + bias +
                    4.0f * (t4.x * lb.x + t4.y * lb.y + t4.z * lb.z + t4.w * lb.w);
        outp[(((size_t)(b * 8 + h)) * 2048 + p) * 128 + d] = (f16)val;
      }
    }
  }
}

// ---------------- fast fused K+V GEMM: 2-phase dbuf pipeline, BK=32 ----------
// XCD swizzle for A-panel L2 reuse; linear LDS + both-sides chunk swizzle;
// one __syncthreads per K-tile: stage(t+1) issued BEFORE compute(t) so the
// 6 global_load_lds are in flight during 32 MFMA (T3 minimum 2-phase).
__global__ void __launch_bounds__(256, 3) kv_gemm_fast_kernel(
    const f16* __restrict__ zph, const f16* __restrict__ zpl,
    const f16* __restrict__ Wh, const unsigned* __restrict__ absmax,
    const float* __restrict__ qbias, const float* __restrict__ tk,
    const float* __restrict__ tv, const float* __restrict__ LBk,
    const float* __restrict__ LBv, f16* __restrict__ kout, f16* __restrict__ vout) {
  __shared__ __align__(16) f16 sbuf[24576];  // 48 KB: [phase][3 streams][4096]
  __shared__ float sT[128][4];

  int linear = blockIdx.x + (blockIdx.y << 4);
  int xcd = linear & 7;
  int slot = linear >> 3;            // 0..511
  int nb = slot & 15;                // 16 nb consecutive per XCD queue
  int g = ((slot >> 4) << 3) + xcd;  // 0..255
  int m0 = g << 7;

  bool is_v = nb >= 8;
  int n0 = (nb & 7) * 128;
  int mat = is_v ? 2 : 1;
  int h = nb & 7;
  const f16* Wm = Wh + (size_t)mat * 1048576;
  const float* ttv = is_v ? tv : tk;
  const float* LBm = is_v ? LBv : LBk;
  const float* qb = qbias + mat * 1024;
  f16* outp = is_v ? vout : kout;

  int tid = threadIdx.x;
  int lane = tid & 63, wave = tid >> 6;
  int wm = (wave >> 1) * 64, wn = (wave & 1) * 64;
  int row = lane & 15, kq = lane >> 4;

  const f16* src0 = zph + (size_t)m0 * 1024;
  const f16* src1 = zpl + (size_t)m0 * 1024;
  const f16* src2 = Wm + (size_t)n0 * 1024;

  // staging: 512 chunks/stream/tile, 2 rounds x 256 threads
  int goff[2], lbase[2];
  #pragma unroll
  for (int r = 0; r < 2; ++r) {
    int L = r * 256 + tid;
    int rw = L >> 2, cc = L & 3;
    int cs = cc ^ (rw & 3) ^ ((rw >> 2) & 3);
    goff[r] = rw * 1024 + cs * 8;      // f16 elems; + t*32 in loop
    lbase[r] = r * 2048 + wave * 512;  // wave-uniform f16 index
  }

  f32x4 acc[4][4];
  #pragma unroll
  for (int i = 0; i < 4; ++i)
    #pragma unroll
    for (int j = 0; j < 4; ++j) acc[i][j] = (f32x4){0.f, 0.f, 0.f, 0.f};

  // per-lane read addresses (f16 offsets within a stream buffer)
  int radA[4], radB[4];
  #pragma unroll
  for (int mi = 0; mi < 4; ++mi) {
    int R = wm + mi * 16 + row;
    radA[mi] = R * 32 + ((kq ^ (R & 3) ^ ((R >> 2) & 3)) << 3);
    int Rb = wn + mi * 16 + row;
    radB[mi] = Rb * 32 + ((kq ^ (Rb & 3) ^ ((Rb >> 2) & 3)) << 3);
  }

  // prologue: stage tile 0 into phase 0
  #pragma unroll
  for (int r = 0; r < 2; ++r) {
    gload16(src0 + goff[r], sbuf + lbase[r]);
    gload16(src1 + goff[r], sbuf + 4096 + lbase[r]);
    gload16(src2 + goff[r], sbuf + 8192 + lbase[r]);
  }
  __syncthreads();

  int cur = 0;
  for (int t = 0; t < 32; ++t) {
    // issue next tile's loads into the other phase (in flight during MFMA)
    if (t < 31) {
      int nxt = (cur ^ 1) * 12288;
      int gk = (t + 1) * 32;
      #pragma unroll
      for (int r = 0; r < 2; ++r) {
        gload16(src0 + goff[r] + gk, sbuf + nxt + lbase[r]);
        gload16(src1 + goff[r] + gk, sbuf + nxt + 4096 + lbase[r]);
        gload16(src2 + goff[r] + gk, sbuf + nxt + 8192 + lbase[r]);
      }
    }
    // compute current tile
    const f16* bAh = sbuf + cur * 12288;
    const f16* bAl = bAh + 4096;
    const f16* bB = bAh + 8192;
    f16x8 ah[4], al[4], bf[4];
    #pragma unroll
    for (int mi = 0; mi < 4; ++mi) {
      ah[mi] = *(const f16x8*)&bAh[radA[mi]];
      al[mi] = *(const f16x8*)&bAl[radA[mi]];
    }
    #pragma unroll
    for (int ni = 0; ni < 4; ++ni) bf[ni] = *(const f16x8*)&bB[radB[ni]];
    #pragma unroll
    for (int mi = 0; mi < 4; ++mi)
      #pragma unroll
      for (int ni = 0; ni < 4; ++ni)
        acc[mi][ni] = __builtin_amdgcn_mfma_f32_16x16x32_f16(ah[mi], bf[ni], acc[mi][ni], 0, 0, 0);
    #pragma unroll
    for (int mi = 0; mi < 4; ++mi)
      #pragma unroll
      for (int ni = 0; ni < 4; ++ni)
        acc[mi][ni] = __builtin_amdgcn_mfma_f32_16x16x32_f16(al[mi], bf[ni], acc[mi][ni], 0, 0, 0);
    __syncthreads();  // drains vmcnt for next tile (loads flew during MFMA)
    cur ^= 1;
  }

  ((float2*)sT)[tid] = ((const float2*)(ttv + (size_t)m0 * 4))[tid];
  __syncthreads();
  float scale = __uint_as_float(absmax[mat]) * (1.0f / 7.0f);
  float biasv[4];
  float4 lbv[4];
  #pragma unroll
  for (int ni = 0; ni < 4; ++ni) {
    int ncol = n0 + wn + ni * 16 + row;
    biasv[ni] = qb[ncol];
    lbv[ni] = *(const float4*)(LBm + ncol * 4);
  }
  float* tbuf = (float*)sbuf;  // 64 x 132 f32 = 33792 B <= 48 KB
  int lh = lane >> 5, l5 = lane & 31;
  #pragma unroll
  for (int halfsel = 0; halfsel < 2; ++halfsel) {
    __syncthreads();
    if ((wave >> 1) == halfsel) {
      #pragma unroll
      for (int ni = 0; ni < 4; ++ni) {
        #pragma unroll
        for (int mi = 0; mi < 4; ++mi) {
          #pragma unroll
          for (int j = 0; j < 4; ++j) {
            int ml = mi * 16 + kq * 4 + j;
            float4 t4 = *(const float4*)&sT[wm + ml][0];
            tbuf[ml * 132 + wn + ni * 16 + row] =
                scale * acc[mi][ni][j] + biasv[ni] +
                4.0f * (t4.x * lbv[ni].x + t4.y * lbv[ni].y + t4.z * lbv[ni].z +
                        t4.w * lbv[ni].w);
          }
        }
      }
    }
    __syncthreads();
    #pragma unroll
    for (int it = 0; it < 8; ++it) {
      int ml = it * 8 + wave * 2 + lh;
      int m = m0 + halfsel * 64 + ml;
      int p = m >> 4, b = m & 15;
      float4 v = *(const float4*)&tbuf[ml * 132 + l5 * 4];
      f16x4 hv = {(f16)v.x, (f16)v.y, (f16)v.z, (f16)v.w};
      *(f16x4*)(outp + (((size_t)(b * 8 + h)) * 2048 + p) * 128 + l5 * 4) = hv;
    }
  }
}

// ---------------- attention (split-P flash over [BH][P][128] f16 KV) -------
__device__ __forceinline__ float4 ld4h(const f16* p) {
  f16x4 v = *reinterpret_cast<const f16x4*>(p);
  return make_float4((float)v[0], (float)v[1], (float)v[2], (float)v[3]);
}

__global__ void __launch_bounds__(256) attn_part_kernel(
    const float* __restrict__ qbuf, const f16* __restrict__ kbuf,
    const f16* __restrict__ vbuf, const float* __restrict__ rel_bias,
    const int* __restrict__ curr_pos_p, float* __restrict__ m_part,
    float* __restrict__ l_part, float* __restrict__ o_part) {
  __shared__ float sS[256];
  __shared__ float red[8];
  __shared__ float sOv[8][132];
  int bh = blockIdx.x;            // b*8+h
  int c = blockIdx.y;             // P chunk
  int b = bh >> 3, h = bh & 7;
  int p0 = c * 256;
  int tid = threadIdx.x, lane = tid & 63, wave = tid >> 6;
  int j4 = lane & 31, ph = lane >> 5;
  float4 qv = *(const float4*)(qbuf + b * 1024 + h * 128 + j4 * 4);
  int off = *curr_pos_p - NP + 64;
  const f16* kb = kbuf + ((size_t)bh * 2048 + p0) * 128;
  for (int i = 0; i < 32; ++i) {
    int pl = i * 8 + wave * 2 + ph;
    float4 kv = ld4h(kb + (size_t)pl * 128 + j4 * 4);
    int idx = min(max(p0 + pl + off, 0), 128);
    float4 rb = *(const float4*)(rel_bias + idx * 1024 + h * 128 + j4 * 4);
    float a = qv.x * (kv.x + rb.x) + qv.y * (kv.y + rb.y) +
              qv.z * (kv.z + rb.z) + qv.w * (kv.w + rb.w);
    a += __shfl_xor(a, 16);
    a += __shfl_xor(a, 8);
    a += __shfl_xor(a, 4);
    a += __shfl_xor(a, 2);
    a += __shfl_xor(a, 1);
    if (j4 == 0) sS[pl] = a * 0.125f;  // 1/sqrt(64)
  }
  __syncthreads();
  float v = sS[tid];
  float mx = v;
  #pragma unroll
  for (int k = 32; k >= 1; k >>= 1) mx = fmaxf(mx, __shfl_xor(mx, k));
  if (lane == 0) red[wave] = mx;
  __syncthreads();
  mx = fmaxf(fmaxf(red[0], red[1]), fmaxf(red[2], red[3]));
  float e = expf(v - mx);
  sS[tid] = e;
  float sum = e;
  #pragma unroll
  for (int k = 32; k >= 1; k >>= 1) sum += __shfl_xor(sum, k);
  if (lane == 0) red[4 + wave] = sum;
  __syncthreads();
  float l = red[4] + red[5] + red[6] + red[7];
  int d4 = tid & 31, pg = tid >> 5;
  const f16* vb = vbuf + ((size_t)bh * 2048 + p0 + pg * 32) * 128;
  float4 a4 = make_float4(0.f, 0.f, 0.f, 0.f);
  #pragma unroll 4
  for (int i = 0; i < 32; ++i) {
    float s = sS[pg * 32 + i];
    float4 vv = ld4h(vb + (size_t)i * 128 + d4 * 4);
    a4.x += s * vv.x;
    a4.y += s * vv.y;
    a4.z += s * vv.z;
    a4.w += s * vv.w;
  }
  *(float4*)&sOv[pg][d4 * 4] = a4;
  __syncthreads();
  if (tid < 128) {
    float o = 0.f;
    #pragma unroll
    for (int gI = 0; gI < 8; ++gI) o += sOv[gI][tid];
    int pc = bh * 8 + c;
    o_part[pc * 128 + tid] = o;
    if (tid == 0) {
      m_part[pc] = mx;
      l_part[pc] = l;
    }
  }
}

__global__ void __launch_bounds__(128) attn_combine_kernel(
    const float* __restrict__ m_part, const float* __restrict__ l_part,
    const float* __restrict__ o_part, float* __restrict__ attout) {
  int bh = blockIdx.x;
  int d = threadIdx.x;
  float M = -1e30f;
  #pragma unroll
  for (int c = 0; c < 8; ++c) M = fmaxf(M, m_part[bh * 8 + c]);
  float L = 0.f, o = 0.f;
  #pragma unroll
  for (int c = 0; c < 8; ++c) {
    float w = expf(m_part[bh * 8 + c] - M);
    L += w * l_part[bh * 8 + c];
    o += w * o_part[(bh * 8 + c) * 128 + d];
  }
  int b = bh >> 3, h = bh & 7;
  attout[b * 1024 + h * 128 + d] = o / L;
}

// ---------------- host launch ----------------
extern "C" void kernel_launch(void* const* d_in, const int* in_sizes, int n_in,
                              void* d_out, int out_size, void* d_ws, size_t ws_size,
                              hipStream_t stream) {
  const int* curr_pos = (const int*)d_in[0];
  const float* z_curr = (const float*)d_in[1];
  const float* z_past = (const float*)d_in[2];
  const float* rel_bias = (const float*)d_in[3];
  const float* Wq = (const float*)d_in[4];
  const float* bq = (const float*)d_in[5];
  const float* Aq = (const float*)d_in[6];
  const float* LBq = (const float*)d_in[7];
  const float* Wk = (const float*)d_in[8];
  const float* bk = (const float*)d_in[9];
  const float* Ak = (const float*)d_in[10];
  const float* LBk = (const float*)d_in[11];
  const float* Wv = (const float*)d_in[12];
  const float* bv = (const float*)d_in[13];
  const float* Av = (const float*)d_in[14];
  const float* LBv = (const float*)d_in[15];
  const float* Wo = (const float*)d_in[16];
  const float* bo = (const float*)d_in[17];
  const float* Ao = (const float*)d_in[18];
  const float* LBo = (const float*)d_in[19];

  char* ws = (char*)d_ws;
  unsigned* absmax = (unsigned*)(ws + OFF_ABSMAX);
  float* t_q = (float*)(ws + OFF_TQ);
  float* t_o = (float*)(ws + OFF_TO);
  float* qbias = (float*)(ws + OFF_QBIAS);
  f16* xqh = (f16*)(ws + OFF_XQH);
  f16* xql = (f16*)(ws + OFF_XQL);
  f16* xoh = (f16*)(ws + OFF_XOH);
  f16* xol = (f16*)(ws + OFF_XOL);
  float* qbuf = (float*)(ws + OFF_QBUF);
  float* attout = (float*)(ws + OFF_ATT);
  float* pm = (float*)(ws + OFF_PM);
  float* pl = (float*)(ws + OFF_PL);
  float* po = (float*)(ws + OFF_PO);
  f16* Wh = (f16*)(ws + OFF_WH);
  float* t_k = (float*)(ws + OFF_TK);
  float* t_v = (float*)(ws + OFF_TV);
  char* kvbase = ws + OFF_KV;

  // always f16 KV: 64 MB each
  f16* kb = (f16*)kvbase;
  f16* vb = (f16*)(kvbase + 67108864ull);
  f16* zph = (f16*)(kvbase + 2ull * 67108864ull);
  f16* zpl = (f16*)(kvbase + 3ull * 67108864ull);
  bool fast = ws_size >= (size_t)OFF_KV + 4ull * 67108864ull;

  hipMemsetAsync(absmax, 0, 16, stream);
  absmax_kernel<<<256, 256, 0, stream>>>(Wq, Wk, Wv, Wo, absmax);
  bias_quant_kernel<<<4, 256, 0, stream>>>(bq, bk, bv, bo, qbias);
  quantW_kernel<<<4096, 256, 0, stream>>>(Wq, Wk, Wv, Wo, absmax, Wh);
  cvt_hilo_kernel<<<16, 256, 0, stream>>>(z_curr, xqh, xql);
  lora_t_small_kernel<<<1, 256, 0, stream>>>(z_curr, Aq, t_q);
  gemv_mfma_kernel<<<16, 256, 0, stream>>>(xqh, xql, Wh, absmax, 0, qbias, t_q, LBq, qbuf);
  lora_t_big_kernel<<<2048, 256, 0, stream>>>(z_past, Ak, Av, t_k, t_v,
                                              fast ? zph : nullptr, fast ? zpl : nullptr);
  if (fast)
    kv_gemm_fast_kernel<<<dim3(16, 256), 256, 0, stream>>>(
        zph, zpl, Wh, absmax, qbias, t_k, t_v, LBk, LBv, kb, vb);
  else
    kv_gemm_kernel<<<dim3(16, 256), 256, 0, stream>>>(
        z_past, Wh, absmax, qbias, t_k, t_v, LBk, LBv, kb, vb);
  attn_part_kernel<<<dim3(128, 8), 256, 0, stream>>>(
      qbuf, kb, vb, rel_bias, curr_pos, pm, pl, po);
  attn_combine_kernel<<<128, 128, 0, stream>>>(pm, pl, po, attout);
  cvt_hilo_kernel<<<16, 256, 0, stream>>>(attout, xoh, xol);
  lora_t_small_kernel<<<1, 256, 0, stream>>>(attout, Ao, t_o);
  gemv_mfma_kernel<<<16, 256, 0, stream>>>(xoh, xol, Wh + 3ull * 1048576ull, absmax, 3,
                                           qbias + 3 * 1024, t_o, LBo, (float*)d_out);
}

// Round 5
// 753.024 us; speedup vs baseline: 1.3344x; 1.0933x over previous
//
#include <hip/hip_runtime.h>
#include <math.h>

typedef _Float16 f16;
typedef _Float16 f16x8 __attribute__((ext_vector_type(8)));
typedef _Float16 f16x4 __attribute__((ext_vector_type(4)));
typedef float f32x4 __attribute__((ext_vector_type(4)));

#define NP 2048
#define M_ROWS 32768

// ---------------- ws layout (bytes) ----------------
#define OFF_ABSMAX 0u
#define OFF_TQ     256u
#define OFF_TO     512u
#define OFF_QBIAS  1024u        // 4*1024 f32
#define OFF_QBUF   163840u      // 16*1024 f32
#define OFF_ATT    229376u      // 16*1024 f32 (ends 294912)
#define OFF_PM     294912u      // 1024 f32 attn partial max
#define OFF_PL     299008u      // 1024 f32 attn partial sum
#define OFF_PO     303104u      // 1024*128 f32 attn partial out (ends 827392)
#define OFF_WH     1048576u     // 4 * 1M f16 = 8 MB
#define OFF_TK     9437184u     // 32768*4 f32
#define OFF_TV     9961472u
#define OFF_KV     10485760u    // kb(64M) vb(64M) zpi(128M) WD(8M)

__device__ __forceinline__ float qint_of(float w, float scale) {
    return fminf(7.f, fmaxf(-8.f, rintf(w / (scale + 1e-8f))));
}

__device__ __forceinline__ void gload16(const void* g, void* l) {
  __builtin_amdgcn_global_load_lds((const __attribute__((address_space(1))) void*)g,
                                   (__attribute__((address_space(3))) void*)l, 16, 0, 0);
}

// ---------------- absmax over 4 weight matrices ----------------
__global__ void __launch_bounds__(256) absmax_kernel(
    const float* __restrict__ W0, const float* __restrict__ W1,
    const float* __restrict__ W2, const float* __restrict__ W3,
    unsigned* __restrict__ absmax) {
  int mat = blockIdx.x >> 6;
  int blk = blockIdx.x & 63;
  const float* W = mat == 0 ? W0 : mat == 1 ? W1 : mat == 2 ? W2 : W3;
  int tid = blk * 256 + threadIdx.x;      // 0..16383
  const float4* W4 = (const float4*)W;
  float m = 0.f;
  #pragma unroll
  for (int i = 0; i < 16; ++i) {
    float4 v = W4[tid + i * 16384];
    m = fmaxf(m, fmaxf(fmaxf(fabsf(v.x), fabsf(v.y)), fmaxf(fabsf(v.z), fabsf(v.w))));
  }
  #pragma unroll
  for (int k = 32; k >= 1; k >>= 1) m = fmaxf(m, __shfl_xor(m, k));
  __shared__ float sm[4];
  if ((threadIdx.x & 63) == 0) sm[threadIdx.x >> 6] = m;
  __syncthreads();
  if (threadIdx.x == 0) {
    m = fmaxf(fmaxf(sm[0], sm[1]), fmaxf(sm[2], sm[3]));
    atomicMax(&absmax[mat], __float_as_uint(m));
  }
}

// ---------------- quantize biases (simq) ----------------
__global__ void __launch_bounds__(256) bias_quant_kernel(
    const float* __restrict__ b0, const float* __restrict__ b1,
    const float* __restrict__ b2, const float* __restrict__ b3,
    float* __restrict__ qbias) {
  int mat = blockIdx.x;
  const float* bb = mat == 0 ? b0 : mat == 1 ? b1 : mat == 2 ? b2 : b3;
  int t = threadIdx.x;
  float4 v = ((const float4*)bb)[t];
  float m = fmaxf(fmaxf(fabsf(v.x), fabsf(v.y)), fmaxf(fabsf(v.z), fabsf(v.w)));
  #pragma unroll
  for (int k = 32; k >= 1; k >>= 1) m = fmaxf(m, __shfl_xor(m, k));
  __shared__ float sm[4];
  if ((t & 63) == 0) sm[t >> 6] = m;
  __syncthreads();
  float M = fmaxf(fmaxf(sm[0], sm[1]), fmaxf(sm[2], sm[3]));
  float scale = M * (1.0f / 7.0f);
  float4 q;
  q.x = (M == 0.f) ? v.x : qint_of(v.x, scale) * scale;
  q.y = (M == 0.f) ? v.y : qint_of(v.y, scale) * scale;
  q.z = (M == 0.f) ? v.z : qint_of(v.z, scale) * scale;
  q.w = (M == 0.f) ? v.w : qint_of(v.w, scale) * scale;
  ((float4*)(qbias + mat * 1024))[t] = q;
}

// ---------------- quantize W -> f16 ints; K/V also duplicated (B') ----------
__global__ void __launch_bounds__(256) quantW_kernel(
    const float* __restrict__ W0, const float* __restrict__ W1,
    const float* __restrict__ W2, const float* __restrict__ W3,
    const unsigned* __restrict__ absmax, f16* __restrict__ Wh,
    f16* __restrict__ WD) {
  int gid = blockIdx.x * 256 + threadIdx.x;  // float4 units
  int mat = gid >> 18;
  int idx = gid & 262143;
  const float* W = mat == 0 ? W0 : mat == 1 ? W1 : mat == 2 ? W2 : W3;
  float scale = __uint_as_float(absmax[mat]) * (1.0f / 7.0f);
  float4 v = ((const float4*)W)[idx];
  f16x4 r;
  r[0] = (f16)qint_of(v.x, scale);
  r[1] = (f16)qint_of(v.y, scale);
  r[2] = (f16)qint_of(v.z, scale);
  r[3] = (f16)qint_of(v.w, scale);
  *(f16x4*)(Wh + (size_t)mat * 1048576 + (size_t)idx * 4) = r;
  if (WD != nullptr && (mat == 1 || mat == 2)) {
    f16x8 d = {r[0], r[0], r[1], r[1], r[2], r[2], r[3], r[3]};
    int n = idx >> 8, c4 = idx & 255;
    *(f16x8*)(WD + (size_t)(mat - 1) * 2097152 + (size_t)n * 2048 + c4 * 8) = d;
  }
}

// ---------------- lora t for 16-row x: t[16][4] ----------------
__global__ void __launch_bounds__(256) lora_t_small_kernel(
    const float* __restrict__ x, const float* __restrict__ A, float* __restrict__ t) {
  int tt = threadIdx.x;
  int b = tt >> 4;
  int r = (tt >> 2) & 3;
  int s = tt & 3;
  const float4* xv = (const float4*)(x + b * 1024 + s * 256);
  const float4* av = (const float4*)(A + r * 1024 + s * 256);
  float acc = 0.f;
  #pragma unroll 4
  for (int i = 0; i < 64; ++i) {
    float4 a = xv[i], c = av[i];
    acc += a.x * c.x + a.y * c.y + a.z * c.z + a.w * c.w;
  }
  acc += __shfl_xor(acc, 1);
  acc += __shfl_xor(acc, 2);
  if (s == 0) t[b * 4 + r] = acc;
}

// ---------------- lora t for z_past + interleaved hi/lo split ----------------
__global__ void __launch_bounds__(256) lora_t_big_kernel(
    const float* __restrict__ zp, const float* __restrict__ Ak,
    const float* __restrict__ Av, float* __restrict__ tk, float* __restrict__ tv,
    f16* __restrict__ zpi) {
  __shared__ float sA[8 * 1024];
  for (int i = 0; i < 8; ++i) {
    int f4 = threadIdx.x + i * 256;
    float4 v = (f4 < 1024) ? ((const float4*)Ak)[f4] : ((const float4*)Av)[f4 - 1024];
    ((float4*)sA)[f4] = v;
  }
  __syncthreads();
  int lane = threadIdx.x & 63, wave = threadIdx.x >> 6;
  for (int it = 0; it < 4; ++it) {
    int m = blockIdx.x * 16 + wave * 4 + it;
    const float4* xr = (const float4*)(zp + (size_t)m * 1024);
    float acc[8] = {0.f, 0.f, 0.f, 0.f, 0.f, 0.f, 0.f, 0.f};
    for (int c = lane; c < 256; c += 64) {
      float4 xv = xr[c];
      if (zpi) {
        f16 h0 = (f16)xv.x, h1 = (f16)xv.y, h2 = (f16)xv.z, h3 = (f16)xv.w;
        f16x8 iv = {h0, (f16)(xv.x - (float)h0), h1, (f16)(xv.y - (float)h1),
                    h2, (f16)(xv.z - (float)h2), h3, (f16)(xv.w - (float)h3)};
        *(f16x8*)(zpi + (size_t)m * 2048 + c * 8) = iv;
      }
      #pragma unroll
      for (int r = 0; r < 8; ++r) {
        float4 a = ((const float4*)sA)[r * 256 + c];
        acc[r] += xv.x * a.x + xv.y * a.y + xv.z * a.z + xv.w * a.w;
      }
    }
    #pragma unroll
    for (int k = 32; k >= 1; k >>= 1) {
      #pragma unroll
      for (int r = 0; r < 8; ++r) acc[r] += __shfl_xor(acc[r], k);
    }
    if (lane == 0) {
      tk[m * 4 + 0] = acc[0]; tk[m * 4 + 1] = acc[1];
      tk[m * 4 + 2] = acc[2]; tk[m * 4 + 3] = acc[3];
      tv[m * 4 + 0] = acc[4]; tv[m * 4 + 1] = acc[5];
      tv[m * 4 + 2] = acc[6]; tv[m * 4 + 3] = acc[7];
    }
  }
}

// ---------------- MFMA GEMV (M=16), f32 input with inline hi/lo -------------
__global__ void __launch_bounds__(256) gemv_mfma_kernel(
    const float* __restrict__ x, const f16* __restrict__ Wm,
    const unsigned* __restrict__ absmax, int mat,
    const float* __restrict__ qb, const float* __restrict__ t,
    const float* __restrict__ LB, float* __restrict__ out) {
  int wave = threadIdx.x >> 6, lane = threadIdx.x & 63;
  int nf = blockIdx.x * 4 + wave;
  int n0 = nf * 16;
  int row = lane & 15, kq = lane >> 4;
  f32x4 acc = {0.f, 0.f, 0.f, 0.f};
  const float* xp = x + row * 1024 + kq * 8;
  const f16* wp = Wm + (size_t)(n0 + row) * 1024 + kq * 8;
  #pragma unroll 4
  for (int k0 = 0; k0 < 1024; k0 += 32) {
    float4 a0 = *(const float4*)(xp + k0);
    float4 a1 = *(const float4*)(xp + k0 + 4);
    f16 h0 = (f16)a0.x, h1 = (f16)a0.y, h2 = (f16)a0.z, h3 = (f16)a0.w;
    f16 h4 = (f16)a1.x, h5 = (f16)a1.y, h6 = (f16)a1.z, h7 = (f16)a1.w;
    f16x8 ah = {h0, h1, h2, h3, h4, h5, h6, h7};
    f16x8 al = {(f16)(a0.x - (float)h0), (f16)(a0.y - (float)h1),
                (f16)(a0.z - (float)h2), (f16)(a0.w - (float)h3),
                (f16)(a1.x - (float)h4), (f16)(a1.y - (float)h5),
                (f16)(a1.z - (float)h6), (f16)(a1.w - (float)h7)};
    f16x8 bb = *(const f16x8*)(wp + k0);
    acc = __builtin_amdgcn_mfma_f32_16x16x32_f16(ah, bb, acc, 0, 0, 0);
    acc = __builtin_amdgcn_mfma_f32_16x16x32_f16(al, bb, acc, 0, 0, 0);
  }
  float scale = __uint_as_float(absmax[mat]) * (1.0f / 7.0f);
  int col = n0 + row;
  float bias = qb[col];
  float4 lb = *(const float4*)(LB + col * 4);
  #pragma unroll
  for (int j = 0; j < 4; ++j) {
    int m = kq * 4 + j;
    float4 tvv = *(const float4*)(t + m * 4);
    out[m * 1024 + col] =
        scale * acc[j] + bias + 4.0f * (tvv.x * lb.x + tvv.y * lb.y + tvv.z * lb.z + tvv.w * lb.w);
  }
}

// ---------------- legacy fused K+V GEMM (reg-staged; fallback) ----
__global__ void __launch_bounds__(256, 2) kv_gemm_kernel(
    const float* __restrict__ zp, const f16* __restrict__ Wh,
    const unsigned* __restrict__ absmax, const float* __restrict__ qbias,
    const float* __restrict__ tk, const float* __restrict__ tv,
    const float* __restrict__ LBk, const float* __restrict__ LBv,
    f16* __restrict__ kout, f16* __restrict__ vout) {
  __shared__ __align__(16) f16 sAh[128][40];
  __shared__ __align__(16) f16 sAl[128][40];
  __shared__ __align__(16) f16 sB[128][40];
  __shared__ float sT[128][4];

  int nb = blockIdx.x;
  int m0 = blockIdx.y * 128;
  bool is_v = nb >= 8;
  int n0 = (nb & 7) * 128;
  int mat = is_v ? 2 : 1;
  const f16* Wm = Wh + (size_t)mat * 1048576;
  const float* ttv = is_v ? tv : tk;
  const float* LBm = is_v ? LBv : LBk;
  const float* qb = qbias + mat * 1024;
  f16* outp = is_v ? vout : kout;

  int tid = threadIdx.x;
  int lane = tid & 63, wave = tid >> 6;
  int wm = (wave >> 1) * 64, wn = (wave & 1) * 64;
  int row = lane & 15, kq = lane >> 4;

  f32x4 acc[4][4];
  #pragma unroll
  for (int i = 0; i < 4; ++i)
    #pragma unroll
    for (int j = 0; j < 4; ++j) acc[i][j] = (f32x4){0.f, 0.f, 0.f, 0.f};

  int sr = tid >> 1, seg = tid & 1;
  const float* asrc = zp + (size_t)(m0 + sr) * 1024 + seg * 16;
  const f16* bsrc = Wm + (size_t)(n0 + sr) * 1024 + seg * 16;

  for (int k0 = 0; k0 < 1024; k0 += 32) {
    __syncthreads();
    float xs[16];
    const float4* a4 = (const float4*)(asrc + k0);
    *(float4*)&xs[0] = a4[0];
    *(float4*)&xs[4] = a4[1];
    *(float4*)&xs[8] = a4[2];
    *(float4*)&xs[12] = a4[3];
    f16 hs[16], ls[16];
    #pragma unroll
    for (int i = 0; i < 16; ++i) {
      f16 h = (f16)xs[i];
      hs[i] = h;
      ls[i] = (f16)(xs[i] - (float)h);
    }
    *(f16x8*)&sAh[sr][seg * 16] = *(f16x8*)&hs[0];
    *(f16x8*)&sAh[sr][seg * 16 + 8] = *(f16x8*)&hs[8];
    *(f16x8*)&sAl[sr][seg * 16] = *(f16x8*)&ls[0];
    *(f16x8*)&sAl[sr][seg * 16 + 8] = *(f16x8*)&ls[8];
    const f16x8* b8 = (const f16x8*)(bsrc + k0);
    *(f16x8*)&sB[sr][seg * 16] = b8[0];
    *(f16x8*)&sB[sr][seg * 16 + 8] = b8[1];
    __syncthreads();
    f16x8 ah[4], al[4], bf[4];
    #pragma unroll
    for (int mi = 0; mi < 4; ++mi) {
      ah[mi] = *(const f16x8*)&sAh[wm + mi * 16 + row][kq * 8];
      al[mi] = *(const f16x8*)&sAl[wm + mi * 16 + row][kq * 8];
    }
    #pragma unroll
    for (int ni = 0; ni < 4; ++ni) bf[ni] = *(const f16x8*)&sB[wn + ni * 16 + row][kq * 8];
    #pragma unroll
    for (int mi = 0; mi < 4; ++mi)
      #pragma unroll
      for (int ni = 0; ni < 4; ++ni)
        acc[mi][ni] = __builtin_amdgcn_mfma_f32_16x16x32_f16(ah[mi], bf[ni], acc[mi][ni], 0, 0, 0);
    #pragma unroll
    for (int mi = 0; mi < 4; ++mi)
      #pragma unroll
      for (int ni = 0; ni < 4; ++ni)
        acc[mi][ni] = __builtin_amdgcn_mfma_f32_16x16x32_f16(al[mi], bf[ni], acc[mi][ni], 0, 0, 0);
  }
  ((float2*)sT)[tid] = ((const float2*)(ttv + (size_t)m0 * 4))[tid];
  __syncthreads();
  float scale = __uint_as_float(absmax[mat]) * (1.0f / 7.0f);
  #pragma unroll
  for (int ni = 0; ni < 4; ++ni) {
    int ncol = n0 + wn + ni * 16 + row;
    int h = ncol >> 7, d = ncol & 127;
    float4 lb = *(const float4*)(LBm + ncol * 4);
    float bias = qb[ncol];
    #pragma unroll
    for (int mi = 0; mi < 4; ++mi) {
      #pragma unroll
      for (int j = 0; j < 4; ++j) {
        int mloc = wm + mi * 16 + kq * 4 + j;
        int m = m0 + mloc;
        int p = m >> 4, b = m & 15;
        float4 t4 = *(const float4*)&sT[mloc][0];
        float val = scale * acc[mi][ni][j] + bias +
                    4.0f * (t4.x * lb.x + t4.y * lb.y + t4.z * lb.z + t4.w * lb.w);
        outp[(((size_t)(b * 8 + h)) * 2048 + p) * 128 + d] = (f16)val;
      }
    }
  }
}

// ---------------- fast fused K+V GEMM: single f16 GEMM over K'=2048 --------
// A' = zpi (hi/lo interleaved), B' = WD (duplicated cols). 2 LDS streams,
// BK'=64, double-buffered (64 KB, 2 blocks/CU), conflict-free XOR-8 swizzle,
// stage(t+1) before compute(t), one barrier per tile. XCD-swizzled grid.
__global__ void __launch_bounds__(256, 2) kv_gemm_fast_kernel(
    const f16* __restrict__ zpi, const f16* __restrict__ WD,
    const unsigned* __restrict__ absmax, const float* __restrict__ qbias,
    const float* __restrict__ tk, const float* __restrict__ tv,
    const float* __restrict__ LBk, const float* __restrict__ LBv,
    f16* __restrict__ kout, f16* __restrict__ vout) {
  __shared__ __align__(16) f16 sbuf[32768];  // 64 KB: [phase][A|B][8192]
  __shared__ float sT[128][4];

  int linear = blockIdx.x + (blockIdx.y << 4);
  int xcd = linear & 7;
  int slot = linear >> 3;            // 0..511
  int nb = slot & 15;                // 16 nb consecutive per XCD queue
  int g = ((slot >> 4) << 3) + xcd;  // 0..255
  int m0 = g << 7;

  bool is_v = nb >= 8;
  int n0 = (nb & 7) * 128;
  int mat = is_v ? 2 : 1;
  int h = nb & 7;
  const float* ttv = is_v ? tv : tk;
  const float* LBm = is_v ? LBv : LBk;
  const float* qb = qbias + mat * 1024;
  f16* outp = is_v ? vout : kout;

  int tid = threadIdx.x;
  int lane = tid & 63, wave = tid >> 6;
  int wm = (wave >> 1) * 64, wn = (wave & 1) * 64;
  int row = lane & 15, kq = lane >> 4;

  const f16* srcA = zpi + (size_t)m0 * 2048;
  const f16* srcB = WD + (size_t)(is_v ? 1 : 0) * 2097152 + (size_t)n0 * 2048;

  // staging: 1024 16B-chunks per stream per tile, 4 rounds x 256 threads
  int goff[4], lbase[4];
  #pragma unroll
  for (int r = 0; r < 4; ++r) {
    int L = r * 256 + tid;
    int rw = L >> 3, cc = L & 7, cs = cc ^ (rw & 7);
    goff[r] = rw * 2048 + cs * 8;      // f16 elems; + t*64 in loop
    lbase[r] = r * 2048 + wave * 512;  // wave-uniform f16 index
  }

  f32x4 acc[4][4];
  #pragma unroll
  for (int i = 0; i < 4; ++i)
    #pragma unroll
    for (int j = 0; j < 4; ++j) acc[i][j] = (f32x4){0.f, 0.f, 0.f, 0.f};

  // per-lane read addrs (f16 offset in a 128x64 stream buffer)
  int radA[8], radB[8];  // [mi*2+ks]
  #pragma unroll
  for (int mi = 0; mi < 4; ++mi) {
    int Ra = wm + mi * 16 + row;
    int Rb = wn + mi * 16 + row;
    #pragma unroll
    for (int ks = 0; ks < 2; ++ks) {
      radA[mi * 2 + ks] = Ra * 64 + (((ks * 4 + kq) ^ (Ra & 7)) << 3);
      radB[mi * 2 + ks] = Rb * 64 + (((ks * 4 + kq) ^ (Rb & 7)) << 3);
    }
  }

  // prologue: stage tile 0 into phase 0
  #pragma unroll
  for (int r = 0; r < 4; ++r) {
    gload16(srcA + goff[r], sbuf + lbase[r]);
    gload16(srcB + goff[r], sbuf + 8192 + lbase[r]);
  }
  __syncthreads();

  int cur = 0;
  for (int t = 0; t < 32; ++t) {
    if (t < 31) {
      int nxt = (cur ^ 1) * 16384;
      int gk = (t + 1) * 64;
      #pragma unroll
      for (int r = 0; r < 4; ++r) {
        gload16(srcA + goff[r] + gk, sbuf + nxt + lbase[r]);
        gload16(srcB + goff[r] + gk, sbuf + nxt + 8192 + lbase[r]);
      }
    }
    const f16* bA = sbuf + cur * 16384;
    const f16* bB = bA + 8192;
    f16x8 af[8], bf[8];
    #pragma unroll
    for (int i = 0; i < 8; ++i) {
      af[i] = *(const f16x8*)&bA[radA[i]];
      bf[i] = *(const f16x8*)&bB[radB[i]];
    }
    #pragma unroll
    for (int ks = 0; ks < 2; ++ks)
      #pragma unroll
      for (int mi = 0; mi < 4; ++mi)
        #pragma unroll
        for (int ni = 0; ni < 4; ++ni)
          acc[mi][ni] = __builtin_amdgcn_mfma_f32_16x16x32_f16(
              af[mi * 2 + ks], bf[ni * 2 + ks], acc[mi][ni], 0, 0, 0);
    __syncthreads();
    cur ^= 1;
  }

  ((float2*)sT)[tid] = ((const float2*)(ttv + (size_t)m0 * 4))[tid];
  __syncthreads();
  float scale = __uint_as_float(absmax[mat]) * (1.0f / 7.0f);
  float biasv[4];
  float4 lbv[4];
  #pragma unroll
  for (int ni = 0; ni < 4; ++ni) {
    int ncol = n0 + wn + ni * 16 + row;
    biasv[ni] = qb[ncol];
    lbv[ni] = *(const float4*)(LBm + ncol * 4);
  }
  float* tbuf = (float*)sbuf;  // 64 x 132 f32 = 33792 B <= 64 KB
  int lh = lane >> 5, l5 = lane & 31;
  #pragma unroll
  for (int halfsel = 0; halfsel < 2; ++halfsel) {
    __syncthreads();
    if ((wave >> 1) == halfsel) {
      #pragma unroll
      for (int ni = 0; ni < 4; ++ni) {
        #pragma unroll
        for (int mi = 0; mi < 4; ++mi) {
          #pragma unroll
          for (int j = 0; j < 4; ++j) {
            int ml = mi * 16 + kq * 4 + j;
            float4 t4 = *(const float4*)&sT[wm + ml][0];
            tbuf[ml * 132 + wn + ni * 16 + row] =
                scale * acc[mi][ni][j] + biasv[ni] +
                4.0f * (t4.x * lbv[ni].x + t4.y * lbv[ni].y + t4.z * lbv[ni].z +
                        t4.w * lbv[ni].w);
          }
        }
      }
    }
    __syncthreads();
    #pragma unroll
    for (int it = 0; it < 8; ++it) {
      int ml = it * 8 + wave * 2 + lh;
      int m = m0 + halfsel * 64 + ml;
      int p = m >> 4, b = m & 15;
      float4 v = *(const float4*)&tbuf[ml * 132 + l5 * 4];
      f16x4 hv = {(f16)v.x, (f16)v.y, (f16)v.z, (f16)v.w};
      *(f16x4*)(outp + (((size_t)(b * 8 + h)) * 2048 + p) * 128 + l5 * 4) = hv;
    }
  }
}

// ---------------- attention (split-P flash over [BH][P][128] f16 KV) -------
__device__ __forceinline__ float4 ld4h(const f16* p) {
  f16x4 v = *reinterpret_cast<const f16x4*>(p);
  return make_float4((float)v[0], (float)v[1], (float)v[2], (float)v[3]);
}

__global__ void __launch_bounds__(256) attn_part_kernel(
    const float* __restrict__ qbuf, const f16* __restrict__ kbuf,
    const f16* __restrict__ vbuf, const float* __restrict__ rel_bias,
    const int* __restrict__ curr_pos_p, float* __restrict__ m_part,
    float* __restrict__ l_part, float* __restrict__ o_part) {
  __shared__ float sS[256];
  __shared__ float red[8];
  __shared__ float sOv[8][132];
  int bh = blockIdx.x;            // b*8+h
  int c = blockIdx.y;             // P chunk
  int b = bh >> 3, h = bh & 7;
  int p0 = c * 256;
  int tid = threadIdx.x, lane = tid & 63, wave = tid >> 6;
  int j4 = lane & 31, ph = lane >> 5;
  float4 qv = *(const float4*)(qbuf + b * 1024 + h * 128 + j4 * 4);
  int off = *curr_pos_p - NP + 64;
  const f16* kb = kbuf + ((size_t)bh * 2048 + p0) * 128;
  for (int i = 0; i < 32; ++i) {
    int pl = i * 8 + wave * 2 + ph;
    float4 kv = ld4h(kb + (size_t)pl * 128 + j4 * 4);
    int idx = min(max(p0 + pl + off, 0), 128);
    float4 rb = *(const float4*)(rel_bias + idx * 1024 + h * 128 + j4 * 4);
    float a = qv.x * (kv.x + rb.x) + qv.y * (kv.y + rb.y) +
              qv.z * (kv.z + rb.z) + qv.w * (kv.w + rb.w);
    a += __shfl_xor(a, 16);
    a += __shfl_xor(a, 8);
    a += __shfl_xor(a, 4);
    a += __shfl_xor(a, 2);
    a += __shfl_xor(a, 1);
    if (j4 == 0) sS[pl] = a * 0.125f;  // 1/sqrt(64)
  }
  __syncthreads();
  float v = sS[tid];
  float mx = v;
  #pragma unroll
  for (int k = 32; k >= 1; k >>= 1) mx = fmaxf(mx, __shfl_xor(mx, k));
  if (lane == 0) red[wave] = mx;
  __syncthreads();
  mx = fmaxf(fmaxf(red[0], red[1]), fmaxf(red[2], red[3]));
  float e = expf(v - mx);
  sS[tid] = e;
  float sum = e;
  #pragma unroll
  for (int k = 32; k >= 1; k >>= 1) sum += __shfl_xor(sum, k);
  if (lane == 0) red[4 + wave] = sum;
  __syncthreads();
  float l = red[4] + red[5] + red[6] + red[7];
  int d4 = tid & 31, pg = tid >> 5;
  const f16* vb = vbuf + ((size_t)bh * 2048 + p0 + pg * 32) * 128;
  float4 a4 = make_float4(0.f, 0.f, 0.f, 0.f);
  #pragma unroll 4
  for (int i = 0; i < 32; ++i) {
    float s = sS[pg * 32 + i];
    float4 vv = ld4h(vb + (size_t)i * 128 + d4 * 4);
    a4.x += s * vv.x;
    a4.y += s * vv.y;
    a4.z += s * vv.z;
    a4.w += s * vv.w;
  }
  *(float4*)&sOv[pg][d4 * 4] = a4;
  __syncthreads();
  if (tid < 128) {
    float o = 0.f;
    #pragma unroll
    for (int gI = 0; gI < 8; ++gI) o += sOv[gI][tid];
    int pc = bh * 8 + c;
    o_part[pc * 128 + tid] = o;
    if (tid == 0) {
      m_part[pc] = mx;
      l_part[pc] = l;
    }
  }
}

__global__ void __launch_bounds__(128) attn_combine_kernel(
    const float* __restrict__ m_part, const float* __restrict__ l_part,
    const float* __restrict__ o_part, float* __restrict__ attout) {
  int bh = blockIdx.x;
  int d = threadIdx.x;
  float M = -1e30f;
  #pragma unroll
  for (int c = 0; c < 8; ++c) M = fmaxf(M, m_part[bh * 8 + c]);
  float L = 0.f, o = 0.f;
  #pragma unroll
  for (int c = 0; c < 8; ++c) {
    float w = expf(m_part[bh * 8 + c] - M);
    L += w * l_part[bh * 8 + c];
    o += w * o_part[(bh * 8 + c) * 128 + d];
  }
  int b = bh >> 3, h = bh & 7;
  attout[b * 1024 + h * 128 + d] = o / L;
}

// ---------------- host launch ----------------
extern "C" void kernel_launch(void* const* d_in, const int* in_sizes, int n_in,
                              void* d_out, int out_size, void* d_ws, size_t ws_size,
                              hipStream_t stream) {
  const int* curr_pos = (const int*)d_in[0];
  const float* z_curr = (const float*)d_in[1];
  const float* z_past = (const float*)d_in[2];
  const float* rel_bias = (const float*)d_in[3];
  const float* Wq = (const float*)d_in[4];
  const float* bq = (const float*)d_in[5];
  const float* Aq = (const float*)d_in[6];
  const float* LBq = (const float*)d_in[7];
  const float* Wk = (const float*)d_in[8];
  const float* bk = (const float*)d_in[9];
  const float* Ak = (const float*)d_in[10];
  const float* LBk = (const float*)d_in[11];
  const float* Wv = (const float*)d_in[12];
  const float* bv = (const float*)d_in[13];
  const float* Av = (const float*)d_in[14];
  const float* LBv = (const float*)d_in[15];
  const float* Wo = (const float*)d_in[16];
  const float* bo = (const float*)d_in[17];
  const float* Ao = (const float*)d_in[18];
  const float* LBo = (const float*)d_in[19];

  char* ws = (char*)d_ws;
  unsigned* absmax = (unsigned*)(ws + OFF_ABSMAX);
  float* t_q = (float*)(ws + OFF_TQ);
  float* t_o = (float*)(ws + OFF_TO);
  float* qbias = (float*)(ws + OFF_QBIAS);
  float* qbuf = (float*)(ws + OFF_QBUF);
  float* attout = (float*)(ws + OFF_ATT);
  float* pm = (float*)(ws + OFF_PM);
  float* pl = (float*)(ws + OFF_PL);
  float* po = (float*)(ws + OFF_PO);
  f16* Wh = (f16*)(ws + OFF_WH);
  float* t_k = (float*)(ws + OFF_TK);
  float* t_v = (float*)(ws + OFF_TV);
  char* kvbase = ws + OFF_KV;

  f16* kb = (f16*)kvbase;                              // 64 MB
  f16* vb = (f16*)(kvbase + 67108864ull);              // 64 MB
  f16* zpi = (f16*)(kvbase + 134217728ull);            // 128 MB
  f16* WD = (f16*)(kvbase + 268435456ull);             // 8 MB
  bool fast = ws_size >= (size_t)OFF_KV + 276824064ull;

  hipMemsetAsync(absmax, 0, 16, stream);
  absmax_kernel<<<256, 256, 0, stream>>>(Wq, Wk, Wv, Wo, absmax);
  bias_quant_kernel<<<4, 256, 0, stream>>>(bq, bk, bv, bo, qbias);
  quantW_kernel<<<4096, 256, 0, stream>>>(Wq, Wk, Wv, Wo, absmax, Wh,
                                          fast ? WD : nullptr);
  lora_t_small_kernel<<<1, 256, 0, stream>>>(z_curr, Aq, t_q);
  gemv_mfma_kernel<<<16, 256, 0, stream>>>(z_curr, Wh, absmax, 0, qbias, t_q, LBq, qbuf);
  lora_t_big_kernel<<<2048, 256, 0, stream>>>(z_past, Ak, Av, t_k, t_v,
                                              fast ? zpi : nullptr);
  if (fast)
    kv_gemm_fast_kernel<<<dim3(16, 256), 256, 0, stream>>>(
        zpi, WD, absmax, qbias, t_k, t_v, LBk, LBv, kb, vb);
  else
    kv_gemm_kernel<<<dim3(16, 256), 256, 0, stream>>>(
        z_past, Wh, absmax, qbias, t_k, t_v, LBk, LBv, kb, vb);
  attn_part_kernel<<<dim3(128, 8), 256, 0, stream>>>(
      qbuf, kb, vb, rel_bias, curr_pos, pm, pl, po);
  attn_combine_kernel<<<128, 128, 0, stream>>>(pm, pl, po, attout);
  lora_t_small_kernel<<<1, 256, 0, stream>>>(attout, Ao, t_o);
  gemv_mfma_kernel<<<16, 256, 0, stream>>>(attout, Wh + 3ull * 1048576ull, absmax, 3,
                                           qbias + 3 * 1024, t_o, LBo, (float*)d_out);
}